// Round 4
// baseline (3444.148 us; speedup 1.0000x reference)
//
#include <hip/hip_runtime.h>
#include <hip/hip_bf16.h>
#include <math.h>

#define B_ 128
#define S_ 2048
#define D_IN_ 512
#define D_MODEL_ 2048
#define M_ 25
#define NSY_ 64
#define H_ 8
#define T_ 10
#define REP_ 2080
#define DH_ 64
#define PRED_N (B_ * 4096)

typedef unsigned short ushort_t;
typedef __bf16 bf16x8 __attribute__((ext_vector_type(8)));
typedef float f32x4 __attribute__((ext_vector_type(4)));
typedef unsigned short us8 __attribute__((ext_vector_type(8)));

__device__ __forceinline__ ushort_t f2bf(float f) {
    __hip_bfloat16 h = __float2bfloat16(f);
    return *(ushort_t*)&h;
}

// ===========================================================================
// Mega-kernel argument block
// ===========================================================================
struct MegaArgs {
    float* qbuf; const ushort_t* Kb; float* scbuf; const int* tokens;
    ushort_t* Pbuf; const ushort_t* VT; float* o_attn; float* obuf;
    const float* bo; const float* bs;
    float* pre0; float* pre1;
    const ushort_t* WoT; const ushort_t* WsT;
    const float* ln_s_g; const float* ln_s_b; float* trace;
    const float* ln_n_g; const float* ln_n_b; const float* Wn; const float* bn;
    const float* temp;
    ushort_t* actb;
    const int* ijtab; const float* r_out; const float* sqb_out; float* a_o; ushort_t* s_outb;
    const float* bout; float* predst;
    const float* r_act; const float* sqb_act; float* a_a; ushort_t* s_actb; const float* bq;
    const ushort_t* WoutT; const ushort_t* WqT;
    unsigned* bcnt; unsigned* bflag;
};

// ---------------------------------------------------------------------------
// Device-scope grid barrier (self-contained; works with ordinary launch and
// graph capture). Requires all blocks co-resident (grid sized via occupancy
// query). cnt/bflag zeroed by init_all inside the same captured graph, so
// every replay resets them. Epoch ep = 1,2,3,... per call site.
// ---------------------------------------------------------------------------
__device__ __forceinline__ void gbar(unsigned* cnt, unsigned* flag, unsigned ep)
{
    __syncthreads();
    if (threadIdx.x == 0) {
        __threadfence();                               // release all prior writes
        const unsigned target = ep * gridDim.x;
        unsigned arrived = __hip_atomic_fetch_add(cnt, 1u, __ATOMIC_RELAXED,
                                                  __HIP_MEMORY_SCOPE_AGENT) + 1u;
        if (arrived == target) {
            __hip_atomic_store(flag, ep, __ATOMIC_RELEASE, __HIP_MEMORY_SCOPE_AGENT);
        } else {
            while (__hip_atomic_load(flag, __ATOMIC_ACQUIRE, __HIP_MEMORY_SCOPE_AGENT) < ep)
                __builtin_amdgcn_s_sleep(8);
        }
        __threadfence();                               // acquire: invalidate caches
    }
    __syncthreads();
}

// ===========================================================================
// Device phase functions (bodies bit-identical to the round-2 kernels)
// ===========================================================================

// 64x128 GEMM tile, atomic epilogue. AF32: A is f32 (cast during staging).
template<bool AF32>
__device__ __forceinline__ void g_tile128(
    const void* Ap, int lda, const ushort_t* Bt, int ldb,
    float* C, int ldc, int nb, int mb, int k0, int k1, char* smem, int tid)
{
    ushort_t (*As)[40] = (ushort_t(*)[40])smem;
    ushort_t (*Bs)[40] = (ushort_t(*)[40])(smem + 64 * 40 * 2);
    const int wave = tid >> 6;
    const int lane = tid & 63;
    const int quad = lane >> 4;
    const int mrow = lane & 15;

    f32x4 acc[4][2];
    #pragma unroll
    for (int s = 0; s < 4; s++)
        #pragma unroll
        for (int u = 0; u < 2; u++)
            acc[s][u] = (f32x4){0.f, 0.f, 0.f, 0.f};

    const int arow = tid >> 2, akc = (tid & 3) * 8;
    const int brow = tid >> 1, bkc = (tid & 1) * 16;

    for (int kk0 = k0; kk0 < k1; kk0 += 32) {
        if (AF32) {
            const float* ap = (const float*)Ap + (size_t)(mb * 64 + arow) * lda + kk0 + akc;
            float4 v0 = *(const float4*)ap;
            float4 v1 = *(const float4*)(ap + 4);
            us8 w = { f2bf(v0.x), f2bf(v0.y), f2bf(v0.z), f2bf(v0.w),
                      f2bf(v1.x), f2bf(v1.y), f2bf(v1.z), f2bf(v1.w) };
            *(us8*)&As[arow][akc] = w;
        } else {
            const ushort_t* ap = (const ushort_t*)Ap + (size_t)(mb * 64 + arow) * lda + kk0 + akc;
            *(us8*)&As[arow][akc] = *(const us8*)ap;
        }
        {
            const ushort_t* bp = Bt + (size_t)(nb * 128 + brow) * ldb + kk0 + bkc;
            *(us8*)&Bs[brow][bkc]     = *(const us8*)bp;
            *(us8*)&Bs[brow][bkc + 8] = *(const us8*)(bp + 8);
        }
        __syncthreads();

        bf16x8 af[4], bfr[2];
        #pragma unroll
        for (int s = 0; s < 4; s++)
            af[s] = *(const bf16x8*)&As[s * 16 + mrow][quad * 8];
        #pragma unroll
        for (int u = 0; u < 2; u++)
            bfr[u] = *(const bf16x8*)&Bs[wave * 32 + u * 16 + mrow][quad * 8];
        #pragma unroll
        for (int s = 0; s < 4; s++)
            #pragma unroll
            for (int u = 0; u < 2; u++)
                acc[s][u] = __builtin_amdgcn_mfma_f32_16x16x32_bf16(
                    af[s], bfr[u], acc[s][u], 0, 0, 0);
        __syncthreads();
    }

    #pragma unroll
    for (int s = 0; s < 4; s++)
        #pragma unroll
        for (int u = 0; u < 2; u++) {
            const int col = nb * 128 + wave * 32 + u * 16 + mrow;
            #pragma unroll
            for (int reg = 0; reg < 4; reg++) {
                const int row = mb * 64 + s * 16 + quad * 4 + reg;
                atomicAdd(&C[(size_t)row * ldc + col], acc[s][u][reg]);
            }
        }
}

// QK scores: vb in [0,512) -> (nb, mb, z). Direct store * 0.125.
__device__ __forceinline__ void g_qk(
    int vb, const float* q, const ushort_t* Kb, float* sc, char* smem, int tid)
{
    const int nb = vb & 15, mb = (vb >> 4) & 1, z = vb >> 5;
    const int c = z >> 3, h = z & 7;
    ushort_t (*As)[40] = (ushort_t(*)[40])smem;
    ushort_t (*Bs)[40] = (ushort_t(*)[40])(smem + 64 * 40 * 2);
    const int wave = tid >> 6;
    const int lane = tid & 63;
    const int quad = lane >> 4;
    const int mrow = lane & 15;

    f32x4 acc[4][2];
    #pragma unroll
    for (int s = 0; s < 4; s++)
        #pragma unroll
        for (int u = 0; u < 2; u++)
            acc[s][u] = (f32x4){0.f, 0.f, 0.f, 0.f};

    const int arow = tid >> 2, akc = (tid & 3) * 8;
    const int brow = tid >> 1, bkc = (tid & 1) * 16;
    const float* Abase = q + (size_t)h * 64;
    const ushort_t* Bbase = Kb + (size_t)c * S_ * 512 + h * 64;

    #pragma unroll
    for (int kk0 = 0; kk0 < 64; kk0 += 32) {
        {
            const float* ap = Abase + (size_t)(mb * 64 + arow) * 512 + kk0 + akc;
            float4 v0 = *(const float4*)ap;
            float4 v1 = *(const float4*)(ap + 4);
            us8 w = { f2bf(v0.x), f2bf(v0.y), f2bf(v0.z), f2bf(v0.w),
                      f2bf(v1.x), f2bf(v1.y), f2bf(v1.z), f2bf(v1.w) };
            *(us8*)&As[arow][akc] = w;
        }
        {
            const ushort_t* bp = Bbase + (size_t)(nb * 128 + brow) * 512 + kk0 + bkc;
            *(us8*)&Bs[brow][bkc]     = *(const us8*)bp;
            *(us8*)&Bs[brow][bkc + 8] = *(const us8*)(bp + 8);
        }
        __syncthreads();

        bf16x8 af[4], bfr[2];
        #pragma unroll
        for (int s = 0; s < 4; s++)
            af[s] = *(const bf16x8*)&As[s * 16 + mrow][quad * 8];
        #pragma unroll
        for (int u = 0; u < 2; u++)
            bfr[u] = *(const bf16x8*)&Bs[wave * 32 + u * 16 + mrow][quad * 8];
        #pragma unroll
        for (int s = 0; s < 4; s++)
            #pragma unroll
            for (int u = 0; u < 2; u++)
                acc[s][u] = __builtin_amdgcn_mfma_f32_16x16x32_bf16(
                    af[s], bfr[u], acc[s][u], 0, 0, 0);
        __syncthreads();
    }

    float* Cb = sc + (size_t)z * 128 * S_;
    #pragma unroll
    for (int s = 0; s < 4; s++)
        #pragma unroll
        for (int u = 0; u < 2; u++) {
            const int col = nb * 128 + wave * 32 + u * 16 + mrow;
            #pragma unroll
            for (int reg = 0; reg < 4; reg++) {
                const int row = mb * 64 + s * 16 + quad * 4 + reg;
                Cb[(size_t)row * S_ + col] = 0.125f * acc[s][u][reg];
            }
        }
}

// softmax + side jobs. vb in [0,1024) = bh.
// vb<512: arm pre_nxt=bs; vb in [512,576): o_attn=0; vb in [576,640): obuf=bo.
__device__ __forceinline__ void g_soft(
    int vb, const MegaArgs& A, float* pre_nxt, char* smem, int tid)
{
    float* red = (float*)smem;
    const int b = vb >> 3, h = vb & 7;

    if (vb < 512) {
        const int idx = vb * 256 + tid;
        const float4* bs4 = (const float4*)A.bs;
        ((float4*)pre_nxt)[idx] = bs4[idx & 1023];
    } else if (vb < 576) {
        const int idx = (vb - 512) * 256 + tid;
        ((float4*)A.o_attn)[idx] = make_float4(0.f, 0.f, 0.f, 0.f);
    } else if (vb < 640) {
        const int idx = (vb - 576) * 256 + tid;
        const float4* bo4 = (const float4*)A.bo;
        ((float4*)A.obuf)[idx] = bo4[idx & 127];
    }

    const float* sc0 = A.scbuf + ((size_t)h * 128 + b) * S_;
    const float* sc1 = A.scbuf + ((size_t)(8 + h) * 128 + b) * S_;
    const int* trow = A.tokens + (size_t)b * S_;

    int tok[8]; float sel[8];
    float lmax = -1e30f;
    #pragma unroll
    for (int i = 0; i < 8; i++) {
        const int s = tid + i * 256;
        tok[i] = trow[s];
        sel[i] = tok[i] ? sc1[s] : sc0[s];
        lmax = fmaxf(lmax, sel[i]);
    }
    red[tid] = lmax; __syncthreads();
    for (int off = 128; off > 0; off >>= 1) {
        if (tid < off) red[tid] = fmaxf(red[tid], red[tid + off]);
        __syncthreads();
    }
    const float mx = red[0];
    __syncthreads();

    float e[8];
    float lsum = 0.f;
    #pragma unroll
    for (int i = 0; i < 8; i++) {
        e[i] = expf(sel[i] - mx);
        lsum += e[i];
    }
    red[tid] = lsum; __syncthreads();
    for (int off = 128; off > 0; off >>= 1) {
        if (tid < off) red[tid] += red[tid + off];
        __syncthreads();
    }
    const float inv = 1.f / red[0];

    ushort_t* Pb = A.Pbuf + ((size_t)h * 128 + b) * 4096;
    #pragma unroll
    for (int i = 0; i < 8; i++) {
        const int s = tid + i * 256;
        const unsigned p = (unsigned)f2bf(e[i] * inv);
        const unsigned word = tok[i] ? (p << 16) : p;
        *(unsigned*)&Pb[s * 2] = word;
    }
    __syncthreads();
}

// PV: vb in [0,128) -> (mb, h, zb).
__device__ __forceinline__ void g_pv(
    int vb, const ushort_t* P, const ushort_t* VT, float* o, char* smem, int tid)
{
    const int mb = vb & 1, h = (vb >> 1) & 7, zb = vb >> 4;
    const int k0 = zb * 512;
    ushort_t (*As)[40] = (ushort_t(*)[40])smem;
    ushort_t (*Bs)[40] = (ushort_t(*)[40])(smem + 64 * 40 * 2);
    const int wave = tid >> 6;
    const int lane = tid & 63;
    const int quad = lane >> 4;
    const int mrow = lane & 15;

    f32x4 acc[4];
    #pragma unroll
    for (int s = 0; s < 4; s++) acc[s] = (f32x4){0.f, 0.f, 0.f, 0.f};

    const int row = tid >> 2, kc = (tid & 3) * 8;
    const ushort_t* Ab = P  + ((size_t)h * 128 + mb * 64 + row) * 4096;
    const ushort_t* Bb = VT + ((size_t)h * 64 + row) * 4096;

    for (int kk = k0; kk < k0 + 512; kk += 32) {
        *(us8*)&As[row][kc] = *(const us8*)(Ab + kk + kc);
        *(us8*)&Bs[row][kc] = *(const us8*)(Bb + kk + kc);
        __syncthreads();
        bf16x8 bfr = *(const bf16x8*)&Bs[wave * 16 + mrow][quad * 8];
        #pragma unroll
        for (int s = 0; s < 4; s++) {
            bf16x8 af = *(const bf16x8*)&As[s * 16 + mrow][quad * 8];
            acc[s] = __builtin_amdgcn_mfma_f32_16x16x32_bf16(af, bfr, acc[s], 0, 0, 0);
        }
        __syncthreads();
    }

    const int col = h * 64 + wave * 16 + mrow;
    #pragma unroll
    for (int s = 0; s < 4; s++)
        #pragma unroll
        for (int reg = 0; reg < 4; reg++) {
            const int rowi = mb * 64 + s * 16 + quad * 4 + reg;
            atomicAdd(&o[(size_t)rowi * 512 + col], acc[s][reg]);
        }
}

// state/trace/act + fused syncs. vb in [0,512): b = vb>>2, quarter q = vb&3.
__device__ __forceinline__ void g_st(
    int vb, int t, int do_act, const float* pre, float* predt,
    const MegaArgs& A, char* smem, int tid)
{
    const int b = vb >> 2, q = vb & 3;
    float* v   = (float*)smem;          // 2048
    float* r1  = v + 2048;              // 256
    float* r2  = r1 + 256;              // 256
    float* shs = r2 + 256;              // 64

    float s1 = 0.f, s2 = 0.f;
    #pragma unroll
    for (int i = 0; i < 8; i++) {
        const int dd = tid + i * 256;
        const float g1 = pre[(size_t)b * 4096 + dd];
        const float g2 = pre[(size_t)b * 4096 + 2048 + dd];
        const float val = g1 * (1.f / (1.f + expf(-g2)));
        v[dd] = val; s1 += val; s2 += val * val;
    }
    r1[tid] = s1; r2[tid] = s2; __syncthreads();
    for (int off = 128; off > 0; off >>= 1) {
        if (tid < off) { r1[tid] += r1[tid + off]; r2[tid] += r2[tid + off]; }
        __syncthreads();
    }
    const float mu = r1[0] * (1.f / D_MODEL_);
    const float var = fmaxf(r2[0] * (1.f / D_MODEL_) - mu * mu, 0.f);
    const float sinv = 1.f / sqrtf(var + 1e-5f);
    const float tval = A.temp[0];

    #pragma unroll
    for (int i = 0; i < 2; i++) {
        const int n = q * 512 + i * 256 + tid;
        const float sval = (v[n] - mu) * sinv * A.ln_s_g[n] + A.ln_s_b[n];
        const int gid = b * 2048 + n;
        float* tr = A.trace + (size_t)gid * M_;
        float x[M_];
        #pragma unroll
        for (int m = 0; m < M_ - 1; m++) x[m] = tr[m + 1];
        x[M_ - 1] = sval;
        #pragma unroll
        for (int m = 0; m < M_; m++) tr[m] = x[m];
        float t1 = 0.f, t2 = 0.f;
        #pragma unroll
        for (int m = 0; m < M_; m++) { t1 += x[m]; t2 += x[m] * x[m]; }
        const float tmu = t1 * (1.f / M_);
        const float tvar = fmaxf(t2 * (1.f / M_) - tmu * tmu, 0.f);
        const float tinv = 1.f / sqrtf(tvar + 1e-5f);
        float y0 = A.bn[n * 2 + 0], y1 = A.bn[n * 2 + 1];
        #pragma unroll
        for (int m = 0; m < M_; m++) {
            const float xn = (x[m] - tmu) * tinv * A.ln_n_g[m] + A.ln_n_b[m];
            y0 += xn * A.Wn[(size_t)(m * 2 + 0) * D_MODEL_ + n];
            y1 += xn * A.Wn[(size_t)(m * 2 + 1) * D_MODEL_ + n];
        }
        const float a = y0 * (1.f / (1.f + expf(-y1))) / tval;
        A.actb[gid] = f2bf(a);
        if (q == 0) {
            if (i == 0 && tid < 64) shs[tid] = a;            // act[b, 0..63]
        } else if (q == 3) {
            if (i == 1 && tid >= 192) shs[tid - 192] = a;    // act[b, 1984..2047]
        }
    }
    __syncthreads();

    if (q == 0) {
        for (int p = tid; p < REP_; p += 256) {
            const int ij = A.ijtab[p];
            const float pair = shs[ij >> 16] * shs[ij & 0xffff];
            const float r = A.r_out[p];
            float a2;
            if (t == 0) a2 = pair;
            else        a2 = r * A.a_o[(size_t)b * REP_ + p] + pair;
            A.a_o[(size_t)b * REP_ + p] = a2;
            A.s_outb[(size_t)b * REP_ + p] = f2bf(a2 / A.sqb_out[(size_t)t * REP_ + p]);
        }
        const float4* b4 = (const float4*)A.bout;
        float4* pd = (float4*)(predt + (size_t)b * 4096);
        for (int idx = tid; idx < 1024; idx += 256) pd[idx] = b4[idx];
    } else if (q == 3 && do_act) {
        for (int p = tid; p < REP_; p += 256) {
            const int ij = A.ijtab[p];
            const float pair = shs[ij >> 16] * shs[ij & 0xffff];
            const float r = A.r_act[p];
            float a2 = r * A.a_a[(size_t)b * REP_ + p] + pair;   // t+1 >= 1
            A.a_a[(size_t)b * REP_ + p] = a2;
            A.s_actb[(size_t)b * REP_ + p] = f2bf(a2 / A.sqb_act[(size_t)(t + 1) * REP_ + p]);
        }
        const float4* b4 = (const float4*)A.bq;
        float4* qb = (float4*)(A.qbuf + (size_t)b * 512);
        if (tid < 128) qb[tid] = b4[tid];
    }
    __syncthreads();
}

// ===========================================================================
// The mega kernel: the entire T-loop, phases separated by manual grid barriers.
// ===========================================================================
__global__ __launch_bounds__(256) void mega_kernel(MegaArgs A)
{
    __shared__ __align__(16) char smem[16384];
    const int tid = threadIdx.x;
    const int gsz = (int)gridDim.x;
    unsigned ep = 0;

    for (int t = 0; t < T_; t++) {
        float* pre_cur = (t & 1) ? A.pre1 : A.pre0;
        float* pre_nxt = (t & 1) ? A.pre0 : A.pre1;
        float* predt = A.predst + (size_t)t * PRED_N;
        const int do_act = (t < T_ - 1) ? 1 : 0;

        // P1: QK scores
        for (int vb = blockIdx.x; vb < 512; vb += gsz)
            g_qk(vb, A.qbuf, A.Kb, A.scbuf, smem, tid);
        gbar(A.bcnt, A.bflag, ++ep);

        // P2: softmax + arms (pre_nxt=bs, o_attn=0, obuf=bo)
        for (int vb = blockIdx.x; vb < 1024; vb += gsz)
            g_soft(vb, A, pre_nxt, smem, tid);
        gbar(A.bcnt, A.bflag, ++ep);

        // P3: PV
        for (int vb = blockIdx.x; vb < 128; vb += gsz)
            g_pv(vb, A.Pbuf, A.VT, A.o_attn, smem, tid);
        gbar(A.bcnt, A.bflag, ++ep);

        // P4: Wo (o_attn @ WoT -> obuf)
        for (int vb = blockIdx.x; vb < 64; vb += gsz) {
            const int nb = vb & 3, mb = (vb >> 2) & 1, zb = vb >> 3;
            g_tile128<true>(A.o_attn, 512, A.WoT, 512, A.obuf, 512,
                            nb, mb, zb * 64, zb * 64 + 64, smem, tid);
        }
        gbar(A.bcnt, A.bflag, ++ep);

        // P5: WsO (obuf @ WsT[:,k<512] -> pre_cur)
        for (int vb = blockIdx.x; vb < 256; vb += gsz) {
            const int nb = vb & 31, mb = (vb >> 5) & 1, zb = vb >> 6;
            g_tile128<true>(A.obuf, 512, A.WsT, 2560, pre_cur, 4096,
                            nb, mb, zb * 128, zb * 128 + 128, smem, tid);
        }
        gbar(A.bcnt, A.bflag, ++ep);

        // P6: state/trace/act + sync_out(t) + predt=bout + sync_act(t+1) + qbuf=bq
        for (int vb = blockIdx.x; vb < 512; vb += gsz)
            g_st(vb, t, do_act, pre_cur, predt, A, smem, tid);
        gbar(A.bcnt, A.bflag, ++ep);

        // P7: Wout(t) [320] + q(t+1) [104] + Ws_act(t+1) [512]
        const int nvb7 = do_act ? 936 : 320;
        for (int vb = blockIdx.x; vb < nvb7; vb += gsz) {
            if (vb < 320) {
                const int nb = vb & 31, mb = (vb >> 5) & 1, zb = vb >> 6;
                const int k0 = zb * 416;
                g_tile128<false>(A.s_outb, REP_, A.WoutT, REP_, predt, 4096,
                                 nb, mb, k0, min(REP_, k0 + 416), smem, tid);
            } else if (vb < 424) {
                const int v2 = vb - 320;
                const int nb = v2 & 3, mb = (v2 >> 2) & 1, zb = v2 >> 3;
                const int k0 = zb * 160;
                g_tile128<false>(A.s_actb, REP_, A.WqT, REP_, A.qbuf, 512,
                                 nb, mb, k0, min(REP_, k0 + 160), smem, tid);
            } else {
                const int v3 = vb - 424;
                const int nb = v3 & 31, mb = (v3 >> 5) & 1, zb = v3 >> 6;
                const int k0 = zb * 256;
                g_tile128<false>(A.actb, 2048, A.WsT + 512, 2560, pre_nxt, 4096,
                                 nb, mb, k0, k0 + 256, smem, tid);
            }
        }
        gbar(A.bcnt, A.bflag, ++ep);
    }
}

// ===========================================================================
// Prologue / epilogue kernels
// ===========================================================================

// MFMA bf16 GEMM, f32 A: used for K/V tables (z==1 path, direct store + bias)
__global__ __launch_bounds__(256) void gemm_bf16(
    const float* __restrict__ A, int lda,
    const ushort_t* __restrict__ Bt, int ldb,
    const float* __restrict__ bias,
    float* __restrict__ C, int ldc,
    int M, int N, int K, int kchunk)
{
    const int nb = blockIdx.x, mb = blockIdx.y, zb = blockIdx.z;
    const int k0 = zb * kchunk;
    const int k1 = min(K, k0 + kchunk);
    __shared__ ushort_t As[64][40];
    __shared__ ushort_t Bs[128][40];

    const int tid  = threadIdx.x;
    const int wave = tid >> 6;
    const int lane = tid & 63;
    const int quad = lane >> 4;
    const int mrow = lane & 15;

    f32x4 acc[4][2];
    #pragma unroll
    for (int s = 0; s < 4; s++)
        #pragma unroll
        for (int u = 0; u < 2; u++)
            acc[s][u] = (f32x4){0.f, 0.f, 0.f, 0.f};

    const int arow = tid >> 2, akc = (tid & 3) * 8;
    const int brow = tid >> 1, bkc = (tid & 1) * 16;

    for (int kk0 = k0; kk0 < k1; kk0 += 32) {
        {
            const float* ap = A + (size_t)(mb * 64 + arow) * lda + kk0 + akc;
            float4 v0 = *(const float4*)ap;
            float4 v1 = *(const float4*)(ap + 4);
            us8 w = { f2bf(v0.x), f2bf(v0.y), f2bf(v0.z), f2bf(v0.w),
                      f2bf(v1.x), f2bf(v1.y), f2bf(v1.z), f2bf(v1.w) };
            *(us8*)&As[arow][akc] = w;
        }
        {
            const ushort_t* bp = Bt + (size_t)(nb * 128 + brow) * ldb + kk0 + bkc;
            *(us8*)&Bs[brow][bkc]     = *(const us8*)bp;
            *(us8*)&Bs[brow][bkc + 8] = *(const us8*)(bp + 8);
        }
        __syncthreads();

        bf16x8 af[4], bfr[2];
        #pragma unroll
        for (int s = 0; s < 4; s++)
            af[s] = *(const bf16x8*)&As[s * 16 + mrow][quad * 8];
        #pragma unroll
        for (int u = 0; u < 2; u++)
            bfr[u] = *(const bf16x8*)&Bs[wave * 32 + u * 16 + mrow][quad * 8];
        #pragma unroll
        for (int s = 0; s < 4; s++)
            #pragma unroll
            for (int u = 0; u < 2; u++)
                acc[s][u] = __builtin_amdgcn_mfma_f32_16x16x32_bf16(
                    af[s], bfr[u], acc[s][u], 0, 0, 0);
        __syncthreads();
    }

    if (gridDim.z == 1) {
        #pragma unroll
        for (int s = 0; s < 4; s++)
            #pragma unroll
            for (int u = 0; u < 2; u++) {
                const int col = nb * 128 + wave * 32 + u * 16 + mrow;
                #pragma unroll
                for (int reg = 0; reg < 4; reg++) {
                    const int row = mb * 64 + s * 16 + quad * 4 + reg;
                    C[(size_t)row * ldc + col] = acc[s][u][reg] + bias[col];
                }
            }
    } else {
        #pragma unroll
        for (int s = 0; s < 4; s++)
            #pragma unroll
            for (int u = 0; u < 2; u++) {
                const int col = nb * 128 + wave * 32 + u * 16 + mrow;
                #pragma unroll
                for (int reg = 0; reg < 4; reg++) {
                    const int row = mb * 64 + s * 16 + quad * 4 + reg;
                    atomicAdd(&C[(size_t)row * ldc + col], acc[s][u][reg]);
                }
            }
    }
}

// bf16-A GEMM (prologue q(0), Ws_act(0))
__global__ __launch_bounds__(256) void gemm_bb(
    const ushort_t* __restrict__ A, int lda,
    const ushort_t* __restrict__ Bt, int ldb,
    const float* __restrict__ bias,
    float* __restrict__ C, int ldc,
    int M, int N, int K, int kchunk)
{
    const int nb = blockIdx.x, mb = blockIdx.y, zb = blockIdx.z;
    const int k0 = zb * kchunk;
    const int k1 = min(K, k0 + kchunk);
    __shared__ ushort_t As[64][40];
    __shared__ ushort_t Bs[128][40];

    const int tid  = threadIdx.x;
    const int wave = tid >> 6;
    const int lane = tid & 63;
    const int quad = lane >> 4;
    const int mrow = lane & 15;

    f32x4 acc[4][2];
    #pragma unroll
    for (int s = 0; s < 4; s++)
        #pragma unroll
        for (int u = 0; u < 2; u++)
            acc[s][u] = (f32x4){0.f, 0.f, 0.f, 0.f};

    const int arow = tid >> 2, akc = (tid & 3) * 8;
    const int brow = tid >> 1, bkc = (tid & 1) * 16;

    for (int kk0 = k0; kk0 < k1; kk0 += 32) {
        {
            const ushort_t* ap = A + (size_t)(mb * 64 + arow) * lda + kk0 + akc;
            *(us8*)&As[arow][akc] = *(const us8*)ap;
        }
        {
            const ushort_t* bp = Bt + (size_t)(nb * 128 + brow) * ldb + kk0 + bkc;
            *(us8*)&Bs[brow][bkc]     = *(const us8*)bp;
            *(us8*)&Bs[brow][bkc + 8] = *(const us8*)(bp + 8);
        }
        __syncthreads();

        bf16x8 af[4], bfr[2];
        #pragma unroll
        for (int s = 0; s < 4; s++)
            af[s] = *(const bf16x8*)&As[s * 16 + mrow][quad * 8];
        #pragma unroll
        for (int u = 0; u < 2; u++)
            bfr[u] = *(const bf16x8*)&Bs[wave * 32 + u * 16 + mrow][quad * 8];
        #pragma unroll
        for (int s = 0; s < 4; s++)
            #pragma unroll
            for (int u = 0; u < 2; u++)
                acc[s][u] = __builtin_amdgcn_mfma_f32_16x16x32_bf16(
                    af[s], bfr[u], acc[s][u], 0, 0, 0);
        __syncthreads();
    }

    if (gridDim.z == 1) {
        #pragma unroll
        for (int s = 0; s < 4; s++)
            #pragma unroll
            for (int u = 0; u < 2; u++) {
                const int col = nb * 128 + wave * 32 + u * 16 + mrow;
                #pragma unroll
                for (int reg = 0; reg < 4; reg++) {
                    const int row = mb * 64 + s * 16 + quad * 4 + reg;
                    C[(size_t)row * ldc + col] = acc[s][u][reg] + bias[col];
                }
            }
    } else {
        #pragma unroll
        for (int s = 0; s < 4; s++)
            #pragma unroll
            for (int u = 0; u < 2; u++) {
                const int col = nb * 128 + wave * 32 + u * 16 + mrow;
                #pragma unroll
                for (int reg = 0; reg < 4; reg++) {
                    const int row = mb * 64 + s * 16 + quad * 4 + reg;
                    atomicAdd(&C[(size_t)row * ldc + col], acc[s][u][reg]);
                }
            }
    }
}

// merged init: feats | act(+actb) | trace | sync tables | barrier zero
#define IA_FE 8192
#define IA_AC (IA_FE + 1024)
#define IA_TR (IA_AC + 6400)
#define IA_SY (IA_TR + 9)
#define IA_NB (IA_SY + 1)
__global__ void init_all(const float* __restrict__ emb, const float* __restrict__ Wp,
                         const float* __restrict__ bp, float* __restrict__ f2,
                         const float* __restrict__ sa, float* __restrict__ act,
                         ushort_t* __restrict__ actb,
                         const float* __restrict__ st, float* __restrict__ trace,
                         const float* __restrict__ dec_act, const float* __restrict__ dec_out,
                         int* __restrict__ ijtab, float* __restrict__ r_act,
                         float* __restrict__ r_out, float* __restrict__ sqb_a,
                         float* __restrict__ sqb_o, unsigned* __restrict__ barst)
{
    const int vb = blockIdx.x, tid = threadIdx.x;
    if (vb < IA_FE) {
        const int gid = vb * 256 + tid;
        const int k = gid & 511;
        const int s = (gid >> 9) & (S_ - 1);
        const int c = gid >> 20;
        const float th = 3.14159265358979323846f * (float)s / (float)(S_ - 1);
        f2[gid] = emb[c * 512 + k] + (-sinf(th)) * Wp[k] + cosf(th) * Wp[512 + k] + bp[k];
    } else if (vb < IA_AC) {
        const int gid = (vb - IA_FE) * 256 + tid;
        const int n = gid & 2047;
        const float v = sa[n];
        act[gid] = v;
        actb[gid] = f2bf(v);
    } else if (vb < IA_TR) {
        const int idx4 = (vb - IA_AC) * 256 + tid;
        ((float4*)trace)[idx4] = ((const float4*)st)[idx4 % 12800];
    } else if (vb < IA_SY) {
        const int p = (vb - IA_TR) * 256 + tid;
        if (p >= REP_) return;
        int i = 0, rem = p;
        while (rem >= NSY_ - i) { rem -= NSY_ - i; i++; }
        ijtab[p] = (i << 16) | (i + rem);
        const float ra = expf(-dec_act[p]);
        const float ro = expf(-dec_out[p]);
        r_act[p] = ra; r_out[p] = ro;
        float ba = 1.f, bo2 = 1.f;
        sqb_a[p] = 1.f;
        sqb_o[p] = 1.f;
        for (int t = 1; t < T_; t++) {
            ba  = ra * ba  + 1.f;
            bo2 = ro * bo2 + 1.f;
            sqb_a[(size_t)t * REP_ + p] = sqrtf(ba);
            sqb_o[(size_t)t * REP_ + p] = sqrtf(bo2);
        }
    } else {
        if (tid < 32) barst[tid] = 0u;   // barrier counter + flag reset (every replay)
    }
}

// merged 6-way transpose (f32 -> bf16, out[n][k] = bf16(in[k][n]))
__global__ __launch_bounds__(256) void transpose_all(
    const float* __restrict__ Wk, ushort_t* __restrict__ WkT,
    const float* __restrict__ Wv, ushort_t* __restrict__ WvT,
    const float* __restrict__ Wq, ushort_t* __restrict__ WqT,
    const float* __restrict__ Wo, ushort_t* __restrict__ WoT,
    const float* __restrict__ Ws, ushort_t* __restrict__ WsT,
    const float* __restrict__ Wout, ushort_t* __restrict__ WoutT)
{
    int bid = blockIdx.x;
    const float* in; ushort_t* out; int K, N;
    if      (bid <   256) {              in = Wk;   out = WkT;   K = 512;  N = 512;  }
    else if (bid <   512) { bid -=  256; in = Wv;   out = WvT;   K = 512;  N = 512;  }
    else if (bid <  1552) { bid -=  512; in = Wq;   out = WqT;   K = 2080; N = 512;  }
    else if (bid <  1808) { bid -= 1552; in = Wo;   out = WoT;   K = 512;  N = 512;  }
    else if (bid < 12048) { bid -= 1808; in = Ws;   out = WsT;   K = 2560; N = 4096; }
    else                  { bid -= 12048; in = Wout; out = WoutT; K = 2080; N = 4096; }
    const int bxw = N >> 5;
    const int bx = bid % bxw, by = bid / bxw;
    __shared__ float tile[32][33];
    const int k0 = by * 32, n0 = bx * 32;
    const int tx = threadIdx.x & 31, ty4 = (threadIdx.x >> 5) * 4;
    #pragma unroll
    for (int i = 0; i < 4; i++)
        tile[ty4 + i][tx] = in[(size_t)(k0 + ty4 + i) * N + n0 + tx];
    __syncthreads();
    #pragma unroll
    for (int i = 0; i < 4; i++)
        out[(size_t)(n0 + ty4 + i) * K + k0 + tx] = f2bf(tile[tx][ty4 + i]);
}

__global__ void cast_bf16_kernel(const float* __restrict__ src,
                                 __hip_bfloat16* __restrict__ dst, int n)
{
    const int gid = (blockIdx.x * 256 + threadIdx.x) * 4;
    if (gid >= n) return;
    float4 v = *(const float4*)(src + gid);
    dst[gid + 0] = __float2bfloat16(v.x);
    dst[gid + 1] = __float2bfloat16(v.y);
    dst[gid + 2] = __float2bfloat16(v.z);
    dst[gid + 3] = __float2bfloat16(v.w);
}

__global__ void build_vt(const float* __restrict__ Vtab, ushort_t* __restrict__ VT)
{
    const int gid = blockIdx.x * 256 + threadIdx.x;  // 8*64*4096
    const int k = gid & 4095;
    const int d = (gid >> 12) & 63;
    const int h = gid >> 18;
    const int s = k >> 1, c = k & 1;
    VT[gid] = f2bf(Vtab[((size_t)(c * S_ + s)) * 512 + h * 64 + d]);
}

// prologue-only t=0 action-sync; y==8 block arms qbuf=bq and pre0=bs
__global__ void sync_kernel(const float* __restrict__ act,
                            float* __restrict__ alpha,
                            const float* __restrict__ decay,
                            const int t, const int off,
                            ushort_t* __restrict__ sout,
                            float* __restrict__ ib1, const float* __restrict__ bias1, int iN1,
                            float* __restrict__ ib2, const float* __restrict__ bias2, int iN2)
{
    const int b = blockIdx.x;
    const int tid = threadIdx.x;
    if (blockIdx.y == 8) {
        if (ib1)
            for (int n = tid; n < iN1; n += 256)
                ib1[(size_t)b * iN1 + n] = bias1[n];
        if (ib2)
            for (int n = tid; n < iN2; n += 256)
                ib2[(size_t)b * iN2 + n] = bias2[n];
    }
    const int p = blockIdx.y * 256 + tid;
    if (p >= REP_) return;
    int i = 0, rem = p;
    while (rem >= NSY_ - i) { rem -= NSY_ - i; i++; }
    const int j = i + rem;
    const float si = act[(size_t)b * D_MODEL_ + off + i];
    const float sj = act[(size_t)b * D_MODEL_ + off + j];
    const float pair = si * sj;
    const float r = expf(-decay[p]);
    float a;
    if (t == 0) a = pair;
    else        a = r * alpha[(size_t)b * REP_ + p] + pair;
    alpha[(size_t)b * REP_ + p] = a;
    float bta = 1.f;
    for (int k = 0; k < t; k++) bta = r * bta + 1.f;
    sout[(size_t)b * REP_ + p] = f2bf(a / sqrtf(bta));
}

__global__ __launch_bounds__(256) void ent_all_kernel(
    const float* __restrict__ predst,  // (T, B*4096)
    float* __restrict__ certbf)        // (T, B*2)
{
    const int t = blockIdx.x >> 7;
    const int b = blockIdx.x & 127;
    const int tid = threadIdx.x;
    __shared__ float red[256];
    const float* pr = predst + (size_t)t * PRED_N + (size_t)b * 4096;
    float sum = 0.f;
    #pragma unroll
    for (int i = 0; i < 8; i++) {
        const int s = tid + i * 256;
        const float l0 = pr[2 * s], l1 = pr[2 * s + 1];
        const float mm = fmaxf(l0, l1);
        const float z0 = expf(l0 - mm), z1 = expf(l1 - mm);
        const float Z = z0 + z1;
        const float lz = logf(Z);
        const float p0 = z0 / Z, p1 = z1 / Z;
        const float lp0 = (l0 - mm) - lz, lp1 = (l1 - mm) - lz;
        sum += -(p0 * lp0 + p1 * lp1) * 1.4426950408889634f;
    }
    red[tid] = sum; __syncthreads();
    for (int off = 128; off > 0; off >>= 1) {
        if (tid < off) red[tid] += red[tid + off];
        __syncthreads();
    }
    if (tid == 0) {
        const float ne = red[0] * (1.f / S_);
        certbf[(size_t)t * B_ * 2 + b * 2 + 0] = ne;
        certbf[(size_t)t * B_ * 2 + b * 2 + 1] = 1.f - ne;
    }
}

__global__ __launch_bounds__(256) void finalize_kernel(
    const float* __restrict__ predstage,  // (T, B*4096)
    const float* __restrict__ certbuf,    // (T, B*2)
    float* __restrict__ dout)
{
    __shared__ float tile[T_][1024];
    const int tid = threadIdx.x;
    const int row0 = blockIdx.x * 1024;
    #pragma unroll
    for (int t = 0; t < T_; t++) {
        float4 v = *(const float4*)(predstage + (size_t)t * PRED_N + row0 + tid * 4);
        tile[t][tid * 4 + 0] = v.x; tile[t][tid * 4 + 1] = v.y;
        tile[t][tid * 4 + 2] = v.z; tile[t][tid * 4 + 3] = v.w;
    }
    __syncthreads();
    float buf[40];
    #pragma unroll
    for (int r = 0; r < 4; r++)
        #pragma unroll
        for (int t = 0; t < T_; t++)
            buf[r * 10 + t] = tile[t][tid * 4 + r];
    float* dst = dout + (size_t)(row0 + tid * 4) * T_;
    #pragma unroll
    for (int k = 0; k < 10; k++)
        *(float4*)(dst + k * 4) = make_float4(buf[4*k], buf[4*k+1], buf[4*k+2], buf[4*k+3]);

    if (blockIdx.x == 0 && tid < B_) {
        const int b = tid;
        const size_t base = (size_t)PRED_N * T_;
        #pragma unroll
        for (int t = 0; t < T_; t++) {
            dout[base + (size_t)(b * 2 + 0) * T_ + t] = certbuf[t * B_ * 2 + b * 2 + 0];
            dout[base + (size_t)(b * 2 + 1) * T_ + t] = certbuf[t * B_ * 2 + b * 2 + 1];
        }
    }
}

// ===========================================================================
extern "C" void kernel_launch(void* const* d_in, const int* in_sizes, int n_in,
                              void* d_out, int out_size, void* d_ws, size_t ws_size,
                              hipStream_t stream)
{
    const int*   tokens    = (const int*)  d_in[0];
    const float* emb       = (const float*)d_in[1];
    const float* W_pos     = (const float*)d_in[2];
    const float* b_pos     = (const float*)d_in[3];
    const float* Wq        = (const float*)d_in[4];
    const float* bq        = (const float*)d_in[5];
    const float* Wk        = (const float*)d_in[6];
    const float* bk        = (const float*)d_in[7];
    const float* Wv        = (const float*)d_in[8];
    const float* bv        = (const float*)d_in[9];
    const float* Wo        = (const float*)d_in[10];
    const float* bo        = (const float*)d_in[11];
    const float* Ws        = (const float*)d_in[12];
    const float* bs        = (const float*)d_in[13];
    const float* ln_s_g    = (const float*)d_in[14];
    const float* ln_s_b    = (const float*)d_in[15];
    const float* ln_n_g    = (const float*)d_in[16];
    const float* ln_n_b    = (const float*)d_in[17];
    const float* Wn        = (const float*)d_in[18];
    const float* bn        = (const float*)d_in[19];
    const float* temp      = (const float*)d_in[20];
    const float* Wout      = (const float*)d_in[21];
    const float* bout      = (const float*)d_in[22];
    const float* start_act = (const float*)d_in[23];
    const float* start_tr  = (const float*)d_in[24];
    const float* dec_act   = (const float*)d_in[25];
    const float* dec_out   = (const float*)d_in[26];
    float* out = (float*)d_out;
    float* w = (float*)d_ws;

    // workspace layout (floats)
    size_t off = 0;
    float* f2     = w + off; off += (size_t)2 * S_ * 512;
    float* Ktab   = w + off; off += (size_t)2 * S_ * 512;
    float* Vtab   = w + off; off += (size_t)2 * S_ * 512;
    float* act    = w + off; off += (size_t)B_ * D_MODEL_;
    float* a_a    = w + off; off += (size_t)B_ * REP_;
    float* a_o    = w + off; off += (size_t)B_ * REP_;
    float* qbuf   = w + off; off += (size_t)B_ * 512;
    float* o_attn = w + off; off += (size_t)B_ * 512;
    float* obuf   = w + off; off += (size_t)B_ * 512;
    float* pre0   = w + off; off += (size_t)B_ * 4096;
    float* pre1   = w + off; off += (size_t)B_ * 4096;
    float* trace  = w + off; off += (size_t)B_ * D_MODEL_ * M_;
    float* scbuf  = w + off; off += (size_t)16 * 128 * S_;
    float* predst = w + off; off += (size_t)T_ * PRED_N;
    float* certbf = w + off; off += (size_t)T_ * B_ * 2;
    ushort_t* s_actb = (ushort_t*)(w + off); off += (size_t)B_ * REP_ / 2;
    ushort_t* s_outb = (ushort_t*)(w + off); off += (size_t)B_ * REP_ / 2;
    ushort_t* actb   = (ushort_t*)(w + off); off += (size_t)B_ * D_MODEL_ / 2;
    __hip_bfloat16* Kb = (__hip_bfloat16*)(w + off); off += (size_t)S_ * 512;
    ushort_t* Pbuf  = (ushort_t*)(w + off); off += (size_t)8 * 128 * 4096 / 2;
    ushort_t* VT    = (ushort_t*)(w + off); off += (size_t)8 * 64 * 4096 / 2;
    ushort_t* WkT   = (ushort_t*)(w + off); off += (size_t)512 * 512 / 2;
    ushort_t* WvT   = (ushort_t*)(w + off); off += (size_t)512 * 512 / 2;
    ushort_t* WqT   = (ushort_t*)(w + off); off += (size_t)512 * REP_ / 2;
    ushort_t* WoT   = (ushort_t*)(w + off); off += (size_t)512 * 512 / 2;
    ushort_t* WsT   = (ushort_t*)(w + off); off += (size_t)4096 * 2560 / 2;
    ushort_t* WoutT = (ushort_t*)(w + off); off += (size_t)4096 * REP_ / 2;
    int*   ijtab  = (int*)(w + off); off += REP_;
    float* r_actT = w + off; off += REP_;
    float* r_outT = w + off; off += REP_;
    float* sqb_a  = w + off; off += (size_t)T_ * REP_;
    float* sqb_o  = w + off; off += (size_t)T_ * REP_;
    unsigned* barst = (unsigned*)(w + off); off += 32;   // [0]=cnt, [16]=flag

    // ---- prologue ----
    init_all<<<IA_NB, 256, 0, stream>>>(
        emb, W_pos, b_pos, f2, start_act, act, actb, start_tr, trace,
        dec_act, dec_out, ijtab, r_actT, r_outT, sqb_a, sqb_o, barst);
    transpose_all<<<20368, 256, 0, stream>>>(
        Wk, WkT, Wv, WvT, Wq, WqT, Wo, WoT, Ws, WsT, Wout, WoutT);
    gemm_bf16<<<dim3(4, 64, 1), 256, 0, stream>>>(
        f2, 512, WkT, 512, bk, Ktab, 512, 2 * S_, 512, 512, 512);
    gemm_bf16<<<dim3(4, 64, 1), 256, 0, stream>>>(
        f2, 512, WvT, 512, bv, Vtab, 512, 2 * S_, 512, 512, 512);
    cast_bf16_kernel<<<(2 * S_ * 512 / 4) / 256, 256, 0, stream>>>(Ktab, Kb, 2 * S_ * 512);
    build_vt<<<(8 * 64 * 4096) / 256, 256, 0, stream>>>(Vtab, VT);

    // t=0 action-sync; arms qbuf=bq and pre0=bs
    sync_kernel<<<dim3(B_, 9), 256, 0, stream>>>(
        act, a_a, dec_act, 0, D_MODEL_ - NSY_, s_actb,
        qbuf, bq, 512, pre0, bs, 4096);
    // Ws_act(0): actb @ WsT[:,k>=512] -> pre0
    gemm_bb<<<dim3(32, 2, 8), 256, 0, stream>>>(
        actb, 2048, WsT + 512, 2560, bq, pre0, 4096, B_, 4096, 2048, 256);
    // q(0)
    gemm_bb<<<dim3(4, 2, 13), 256, 0, stream>>>(
        s_actb, REP_, WqT, REP_, bq, qbuf, 512, B_, 512, REP_, 160);

    // ---- the whole T-loop as one kernel with manual grid barriers ----
    MegaArgs ma;
    ma.qbuf = qbuf; ma.Kb = (const ushort_t*)Kb; ma.scbuf = scbuf; ma.tokens = tokens;
    ma.Pbuf = Pbuf; ma.VT = VT; ma.o_attn = o_attn; ma.obuf = obuf;
    ma.bo = bo; ma.bs = bs;
    ma.pre0 = pre0; ma.pre1 = pre1;
    ma.WoT = WoT; ma.WsT = WsT;
    ma.ln_s_g = ln_s_g; ma.ln_s_b = ln_s_b; ma.trace = trace;
    ma.ln_n_g = ln_n_g; ma.ln_n_b = ln_n_b; ma.Wn = Wn; ma.bn = bn;
    ma.temp = temp;
    ma.actb = actb;
    ma.ijtab = ijtab; ma.r_out = r_outT; ma.sqb_out = sqb_o; ma.a_o = a_o; ma.s_outb = s_outb;
    ma.bout = bout; ma.predst = predst;
    ma.r_act = r_actT; ma.sqb_act = sqb_a; ma.a_a = a_a; ma.s_actb = s_actb; ma.bq = bq;
    ma.WoutT = WoutT; ma.WqT = WqT;
    ma.bcnt = barst; ma.bflag = barst + 16;

    static int ncu = 0;
    if (!ncu) {
        hipDeviceProp_t prop;
        if (hipGetDeviceProperties(&prop, 0) == hipSuccess) ncu = prop.multiProcessorCount;
        if (ncu <= 0) ncu = 256;
    }
    int mab = 0;
    hipOccupancyMaxActiveBlocksPerMultiprocessor(&mab, mega_kernel, 256, 0);
    if (mab < 1) mab = 1;
    long grid = (long)mab * ncu;
    if (grid > 1024) grid = 1024;
    if (grid < 1) grid = 1;
    mega_kernel<<<dim3((int)grid), 256, 0, stream>>>(ma);

    // ---- epilogue ----
    ent_all_kernel<<<T_ * B_, 256, 0, stream>>>(predst, certbf);
    finalize_kernel<<<PRED_N / 1024, 256, 0, stream>>>(predst, certbf, out);
}

// Round 5
// 1157.403 us; speedup vs baseline: 2.9758x; 2.9758x over previous
//
#include <hip/hip_runtime.h>
#include <hip/hip_bf16.h>
#include <math.h>

#define B_ 128
#define S_ 2048
#define D_IN_ 512
#define D_MODEL_ 2048
#define M_ 25
#define NSY_ 64
#define H_ 8
#define T_ 10
#define REP_ 2080
#define DH_ 64
#define PRED_N (B_ * 4096)

typedef unsigned short ushort_t;
typedef __bf16 bf16x8 __attribute__((ext_vector_type(8)));
typedef float f32x4 __attribute__((ext_vector_type(4)));
typedef unsigned short us8 __attribute__((ext_vector_type(8)));

__device__ __forceinline__ ushort_t f2bf(float f) {
    __hip_bfloat16 h = __float2bfloat16(f);
    return *(ushort_t*)&h;
}

// ---------------------------------------------------------------------------
// MFMA bf16 GEMM, f32 A (cast during staging): C[M,N] (+)= A @ Bt^T
// grid = (N/128, M/64, Z). Z==1: direct store + bias. Z>1: atomicAdd.
// ---------------------------------------------------------------------------
__global__ __launch_bounds__(256) void gemm_bf16(
    const float* __restrict__ A, int lda,
    const ushort_t* __restrict__ Bt, int ldb,
    const float* __restrict__ bias,
    float* __restrict__ C, int ldc,
    int M, int N, int K, int kchunk)
{
    const int nb = blockIdx.x, mb = blockIdx.y, zb = blockIdx.z;
    const int k0 = zb * kchunk;
    const int k1 = min(K, k0 + kchunk);
    __shared__ ushort_t As[64][40];
    __shared__ ushort_t Bs[128][40];

    const int tid  = threadIdx.x;
    const int wave = tid >> 6;
    const int lane = tid & 63;
    const int quad = lane >> 4;
    const int mrow = lane & 15;

    f32x4 acc[4][2];
    #pragma unroll
    for (int s = 0; s < 4; s++)
        #pragma unroll
        for (int u = 0; u < 2; u++)
            acc[s][u] = (f32x4){0.f, 0.f, 0.f, 0.f};

    const int arow = tid >> 2, akc = (tid & 3) * 8;
    const int brow = tid >> 1, bkc = (tid & 1) * 16;

    for (int kk0 = k0; kk0 < k1; kk0 += 32) {
        {
            const float* ap = A + (size_t)(mb * 64 + arow) * lda + kk0 + akc;
            float4 v0 = *(const float4*)ap;
            float4 v1 = *(const float4*)(ap + 4);
            us8 w = { f2bf(v0.x), f2bf(v0.y), f2bf(v0.z), f2bf(v0.w),
                      f2bf(v1.x), f2bf(v1.y), f2bf(v1.z), f2bf(v1.w) };
            *(us8*)&As[arow][akc] = w;
        }
        {
            const ushort_t* bp = Bt + (size_t)(nb * 128 + brow) * ldb + kk0 + bkc;
            *(us8*)&Bs[brow][bkc]     = *(const us8*)bp;
            *(us8*)&Bs[brow][bkc + 8] = *(const us8*)(bp + 8);
        }
        __syncthreads();

        bf16x8 af[4], bfr[2];
        #pragma unroll
        for (int s = 0; s < 4; s++)
            af[s] = *(const bf16x8*)&As[s * 16 + mrow][quad * 8];
        #pragma unroll
        for (int u = 0; u < 2; u++)
            bfr[u] = *(const bf16x8*)&Bs[wave * 32 + u * 16 + mrow][quad * 8];
        #pragma unroll
        for (int s = 0; s < 4; s++)
            #pragma unroll
            for (int u = 0; u < 2; u++)
                acc[s][u] = __builtin_amdgcn_mfma_f32_16x16x32_bf16(
                    af[s], bfr[u], acc[s][u], 0, 0, 0);
        __syncthreads();
    }

    if (gridDim.z == 1) {
        #pragma unroll
        for (int s = 0; s < 4; s++)
            #pragma unroll
            for (int u = 0; u < 2; u++) {
                const int col = nb * 128 + wave * 32 + u * 16 + mrow;
                #pragma unroll
                for (int reg = 0; reg < 4; reg++) {
                    const int row = mb * 64 + s * 16 + quad * 4 + reg;
                    C[(size_t)row * ldc + col] = acc[s][u][reg] + bias[col];
                }
            }
    } else {
        #pragma unroll
        for (int s = 0; s < 4; s++)
            #pragma unroll
            for (int u = 0; u < 2; u++) {
                const int col = nb * 128 + wave * 32 + u * 16 + mrow;
                #pragma unroll
                for (int reg = 0; reg < 4; reg++) {
                    const int row = mb * 64 + s * 16 + quad * 4 + reg;
                    atomicAdd(&C[(size_t)row * ldc + col], acc[s][u][reg]);
                }
            }
    }
}

// ---------------------------------------------------------------------------
// Same GEMM but A already bf16.
// ---------------------------------------------------------------------------
__global__ __launch_bounds__(256) void gemm_bb(
    const ushort_t* __restrict__ A, int lda,
    const ushort_t* __restrict__ Bt, int ldb,
    const float* __restrict__ bias,
    float* __restrict__ C, int ldc,
    int M, int N, int K, int kchunk)
{
    const int nb = blockIdx.x, mb = blockIdx.y, zb = blockIdx.z;
    const int k0 = zb * kchunk;
    const int k1 = min(K, k0 + kchunk);
    __shared__ ushort_t As[64][40];
    __shared__ ushort_t Bs[128][40];

    const int tid  = threadIdx.x;
    const int wave = tid >> 6;
    const int lane = tid & 63;
    const int quad = lane >> 4;
    const int mrow = lane & 15;

    f32x4 acc[4][2];
    #pragma unroll
    for (int s = 0; s < 4; s++)
        #pragma unroll
        for (int u = 0; u < 2; u++)
            acc[s][u] = (f32x4){0.f, 0.f, 0.f, 0.f};

    const int arow = tid >> 2, akc = (tid & 3) * 8;
    const int brow = tid >> 1, bkc = (tid & 1) * 16;

    for (int kk0 = k0; kk0 < k1; kk0 += 32) {
        {
            const ushort_t* ap = A + (size_t)(mb * 64 + arow) * lda + kk0 + akc;
            *(us8*)&As[arow][akc] = *(const us8*)ap;
        }
        {
            const ushort_t* bp = Bt + (size_t)(nb * 128 + brow) * ldb + kk0 + bkc;
            *(us8*)&Bs[brow][bkc]     = *(const us8*)bp;
            *(us8*)&Bs[brow][bkc + 8] = *(const us8*)(bp + 8);
        }
        __syncthreads();

        bf16x8 af[4], bfr[2];
        #pragma unroll
        for (int s = 0; s < 4; s++)
            af[s] = *(const bf16x8*)&As[s * 16 + mrow][quad * 8];
        #pragma unroll
        for (int u = 0; u < 2; u++)
            bfr[u] = *(const bf16x8*)&Bs[wave * 32 + u * 16 + mrow][quad * 8];
        #pragma unroll
        for (int s = 0; s < 4; s++)
            #pragma unroll
            for (int u = 0; u < 2; u++)
                acc[s][u] = __builtin_amdgcn_mfma_f32_16x16x32_bf16(
                    af[s], bfr[u], acc[s][u], 0, 0, 0);
        __syncthreads();
    }

    if (gridDim.z == 1) {
        #pragma unroll
        for (int s = 0; s < 4; s++)
            #pragma unroll
            for (int u = 0; u < 2; u++) {
                const int col = nb * 128 + wave * 32 + u * 16 + mrow;
                #pragma unroll
                for (int reg = 0; reg < 4; reg++) {
                    const int row = mb * 64 + s * 16 + quad * 4 + reg;
                    C[(size_t)row * ldc + col] = acc[s][u][reg] + bias[col];
                }
            }
    } else {
        #pragma unroll
        for (int s = 0; s < 4; s++)
            #pragma unroll
            for (int u = 0; u < 2; u++) {
                const int col = nb * 128 + wave * 32 + u * 16 + mrow;
                #pragma unroll
                for (int reg = 0; reg < 4; reg++) {
                    const int row = mb * 64 + s * 16 + quad * 4 + reg;
                    atomicAdd(&C[(size_t)row * ldc + col], acc[s][u][reg]);
                }
            }
    }
}

// ---------------------------------------------------------------------------
// Shared 64x128 GEMM tile device fn (atomic epilogue), for triple_kernel.
// ---------------------------------------------------------------------------
__device__ __forceinline__ void g_tile128(
    const ushort_t* Ap, int lda, const ushort_t* Bt, int ldb,
    float* C, int ldc, int nb, int mb, int k0, int k1, char* smem, int tid)
{
    ushort_t (*As)[40] = (ushort_t(*)[40])smem;
    ushort_t (*Bs)[40] = (ushort_t(*)[40])(smem + 64 * 40 * 2);
    const int wave = tid >> 6;
    const int lane = tid & 63;
    const int quad = lane >> 4;
    const int mrow = lane & 15;

    f32x4 acc[4][2];
    #pragma unroll
    for (int s = 0; s < 4; s++)
        #pragma unroll
        for (int u = 0; u < 2; u++)
            acc[s][u] = (f32x4){0.f, 0.f, 0.f, 0.f};

    const int arow = tid >> 2, akc = (tid & 3) * 8;
    const int brow = tid >> 1, bkc = (tid & 1) * 16;

    for (int kk0 = k0; kk0 < k1; kk0 += 32) {
        {
            const ushort_t* ap = Ap + (size_t)(mb * 64 + arow) * lda + kk0 + akc;
            *(us8*)&As[arow][akc] = *(const us8*)ap;
        }
        {
            const ushort_t* bp = Bt + (size_t)(nb * 128 + brow) * ldb + kk0 + bkc;
            *(us8*)&Bs[brow][bkc]     = *(const us8*)bp;
            *(us8*)&Bs[brow][bkc + 8] = *(const us8*)(bp + 8);
        }
        __syncthreads();

        bf16x8 af[4], bfr[2];
        #pragma unroll
        for (int s = 0; s < 4; s++)
            af[s] = *(const bf16x8*)&As[s * 16 + mrow][quad * 8];
        #pragma unroll
        for (int u = 0; u < 2; u++)
            bfr[u] = *(const bf16x8*)&Bs[wave * 32 + u * 16 + mrow][quad * 8];
        #pragma unroll
        for (int s = 0; s < 4; s++)
            #pragma unroll
            for (int u = 0; u < 2; u++)
                acc[s][u] = __builtin_amdgcn_mfma_f32_16x16x32_bf16(
                    af[s], bfr[u], acc[s][u], 0, 0, 0);
        __syncthreads();
    }

    #pragma unroll
    for (int s = 0; s < 4; s++)
        #pragma unroll
        for (int u = 0; u < 2; u++) {
            const int col = nb * 128 + wave * 32 + u * 16 + mrow;
            #pragma unroll
            for (int reg = 0; reg < 4; reg++) {
                const int row = mb * 64 + s * 16 + quad * 4 + reg;
                atomicAdd(&C[(size_t)row * ldc + col], acc[s][u][reg]);
            }
        }
}

// ---------------------------------------------------------------------------
// Merged tail launch: Wout(t) [0,320) + q(t+1) [320,424) + Ws_act(t+1) [424,936)
// (At t=T-1 launch only 320 blocks.)  All targets pre-armed with their bias.
// ---------------------------------------------------------------------------
__global__ __launch_bounds__(256) void triple_kernel(
    const ushort_t* __restrict__ s_outb, const ushort_t* __restrict__ WoutT,
    float* __restrict__ predt,
    const ushort_t* __restrict__ s_actb, const ushort_t* __restrict__ WqT,
    float* __restrict__ qbuf,
    const ushort_t* __restrict__ actb, const ushort_t* __restrict__ WsT,
    float* __restrict__ pre_nxt)
{
    __shared__ __align__(16) char smem[15360];
    const int vb = blockIdx.x, tid = threadIdx.x;
    if (vb < 320) {
        const int nb = vb & 31, mb = (vb >> 5) & 1, zb = vb >> 6;
        const int k0 = zb * 416;
        g_tile128(s_outb, REP_, WoutT, REP_, predt, 4096,
                  nb, mb, k0, min(REP_, k0 + 416), smem, tid);
    } else if (vb < 424) {
        const int v2 = vb - 320;
        const int nb = v2 & 3, mb = (v2 >> 2) & 1, zb = v2 >> 3;
        const int k0 = zb * 160;
        g_tile128(s_actb, REP_, WqT, REP_, qbuf, 512,
                  nb, mb, k0, min(REP_, k0 + 160), smem, tid);
    } else {
        const int v3 = vb - 424;
        const int nb = v3 & 31, mb = (v3 >> 5) & 1, zb = v3 >> 6;
        const int k0 = zb * 256;
        g_tile128(actb, 2048, WsT + 512, 2560, pre_nxt, 4096,
                  nb, mb, k0, k0 + 256, smem, tid);
    }
}

// ---------------------------------------------------------------------------
// QK scores: sc[(c*8+h)*128+b][s] = 0.125 * q_bh . K_chs ; grid (16,2,16)
// ---------------------------------------------------------------------------
__global__ __launch_bounds__(256) void gemm_qk(
    const float* __restrict__ q,
    const ushort_t* __restrict__ Kb,
    float* __restrict__ sc)
{
    const int nb = blockIdx.x, mb = blockIdx.y, z = blockIdx.z;
    const int c = z >> 3, h = z & 7;
    __shared__ ushort_t As[64][40];
    __shared__ ushort_t Bs[128][40];

    const int tid  = threadIdx.x;
    const int wave = tid >> 6;
    const int lane = tid & 63;
    const int quad = lane >> 4;
    const int mrow = lane & 15;

    f32x4 acc[4][2];
    #pragma unroll
    for (int s = 0; s < 4; s++)
        #pragma unroll
        for (int u = 0; u < 2; u++)
            acc[s][u] = (f32x4){0.f, 0.f, 0.f, 0.f};

    const int arow = tid >> 2, akc = (tid & 3) * 8;
    const int brow = tid >> 1, bkc = (tid & 1) * 16;
    const float* Abase = q + (size_t)h * 64;
    const ushort_t* Bbase = Kb + (size_t)c * S_ * 512 + h * 64;

    #pragma unroll
    for (int kk0 = 0; kk0 < 64; kk0 += 32) {
        {
            const float* ap = Abase + (size_t)(mb * 64 + arow) * 512 + kk0 + akc;
            float4 v0 = *(const float4*)ap;
            float4 v1 = *(const float4*)(ap + 4);
            us8 w = { f2bf(v0.x), f2bf(v0.y), f2bf(v0.z), f2bf(v0.w),
                      f2bf(v1.x), f2bf(v1.y), f2bf(v1.z), f2bf(v1.w) };
            *(us8*)&As[arow][akc] = w;
        }
        {
            const ushort_t* bp = Bbase + (size_t)(nb * 128 + brow) * 512 + kk0 + bkc;
            *(us8*)&Bs[brow][bkc]     = *(const us8*)bp;
            *(us8*)&Bs[brow][bkc + 8] = *(const us8*)(bp + 8);
        }
        __syncthreads();

        bf16x8 af[4], bfr[2];
        #pragma unroll
        for (int s = 0; s < 4; s++)
            af[s] = *(const bf16x8*)&As[s * 16 + mrow][quad * 8];
        #pragma unroll
        for (int u = 0; u < 2; u++)
            bfr[u] = *(const bf16x8*)&Bs[wave * 32 + u * 16 + mrow][quad * 8];
        #pragma unroll
        for (int s = 0; s < 4; s++)
            #pragma unroll
            for (int u = 0; u < 2; u++)
                acc[s][u] = __builtin_amdgcn_mfma_f32_16x16x32_bf16(
                    af[s], bfr[u], acc[s][u], 0, 0, 0);
        __syncthreads();
    }

    float* Cb = sc + (size_t)z * 128 * S_;
    #pragma unroll
    for (int s = 0; s < 4; s++)
        #pragma unroll
        for (int u = 0; u < 2; u++) {
            const int col = nb * 128 + wave * 32 + u * 16 + mrow;
            #pragma unroll
            for (int reg = 0; reg < 4; reg++) {
                const int row = mb * 64 + s * 16 + quad * 4 + reg;
                Cb[(size_t)row * S_ + col] = 0.125f * acc[s][u][reg];
            }
        }
}

// ---------------------------------------------------------------------------
// token-select + softmax -> P (bf16 packed). Side jobs:
//   bh<512: arm pre_nxt=bs2 ; bh in [512,576): o_attn=0.
// ---------------------------------------------------------------------------
__global__ __launch_bounds__(256) void attn_soft(
    const float* __restrict__ sc,             // (16,128,2048)
    const int*   __restrict__ tokens,         // (B,S)
    ushort_t* __restrict__ P,                 // (8,128,4096)
    float* __restrict__ o,                    // (B,512) -> zeroed
    const float* __restrict__ bs2,            // (4096)
    float* __restrict__ pre_nxt)              // (B,4096) -> init to bs2
{
    const int bh = blockIdx.x;
    const int b = bh >> 3, h = bh & 7;
    __shared__ float red[256];
    const int tid = threadIdx.x;

    if (bh < 512) {
        const int idx = bh * 256 + tid;
        const float4* bs4 = (const float4*)bs2;
        ((float4*)pre_nxt)[idx] = bs4[idx & 1023];
    } else if (bh < 576) {
        const int idx = (bh - 512) * 256 + tid;
        ((float4*)o)[idx] = make_float4(0.f, 0.f, 0.f, 0.f);
    }

    const float* sc0 = sc + ((size_t)h * 128 + b) * S_;
    const float* sc1 = sc + ((size_t)(8 + h) * 128 + b) * S_;
    const int* trow = tokens + (size_t)b * S_;

    int tok[8]; float sel[8];
    float lmax = -1e30f;
    #pragma unroll
    for (int i = 0; i < 8; i++) {
        const int s = tid + i * 256;
        tok[i] = trow[s];
        sel[i] = tok[i] ? sc1[s] : sc0[s];
        lmax = fmaxf(lmax, sel[i]);
    }
    red[tid] = lmax; __syncthreads();
    for (int off = 128; off > 0; off >>= 1) {
        if (tid < off) red[tid] = fmaxf(red[tid], red[tid + off]);
        __syncthreads();
    }
    const float mx = red[0];
    __syncthreads();

    float e[8];
    float lsum = 0.f;
    #pragma unroll
    for (int i = 0; i < 8; i++) {
        e[i] = expf(sel[i] - mx);
        lsum += e[i];
    }
    red[tid] = lsum; __syncthreads();
    for (int off = 128; off > 0; off >>= 1) {
        if (tid < off) red[tid] += red[tid + off];
        __syncthreads();
    }
    const float inv = 1.f / red[0];

    ushort_t* Pb = P + ((size_t)h * 128 + b) * 4096;
    #pragma unroll
    for (int i = 0; i < 8; i++) {
        const int s = tid + i * 256;
        const unsigned p = (unsigned)f2bf(e[i] * inv);
        const unsigned word = tok[i] ? (p << 16) : p;
        *(unsigned*)&Pb[s * 2] = word;
    }
}

// ---------------------------------------------------------------------------
// PV via MFMA. grid (2, 8, 8). atomicAdd into pre-zeroed o.
// ---------------------------------------------------------------------------
__global__ __launch_bounds__(256) void gemm_pv(
    const ushort_t* __restrict__ P,    // (8,128,4096)
    const ushort_t* __restrict__ VT,   // (8,64,4096)
    float* __restrict__ o)             // (128,512)
{
    const int mb = blockIdx.x, h = blockIdx.y, zb = blockIdx.z;
    const int k0 = zb * 512;
    __shared__ ushort_t As[64][40];
    __shared__ ushort_t Bs[64][40];

    const int tid  = threadIdx.x;
    const int wave = tid >> 6;
    const int lane = tid & 63;
    const int quad = lane >> 4;
    const int mrow = lane & 15;

    f32x4 acc[4];
    #pragma unroll
    for (int s = 0; s < 4; s++) acc[s] = (f32x4){0.f, 0.f, 0.f, 0.f};

    const int row = tid >> 2, kc = (tid & 3) * 8;
    const ushort_t* Ab = P  + ((size_t)h * 128 + mb * 64 + row) * 4096;
    const ushort_t* Bb = VT + ((size_t)h * 64 + row) * 4096;

    for (int kk = k0; kk < k0 + 512; kk += 32) {
        *(us8*)&As[row][kc] = *(const us8*)(Ab + kk + kc);
        *(us8*)&Bs[row][kc] = *(const us8*)(Bb + kk + kc);
        __syncthreads();
        bf16x8 bfr = *(const bf16x8*)&Bs[wave * 16 + mrow][quad * 8];
        #pragma unroll
        for (int s = 0; s < 4; s++) {
            bf16x8 af = *(const bf16x8*)&As[s * 16 + mrow][quad * 8];
            acc[s] = __builtin_amdgcn_mfma_f32_16x16x32_bf16(af, bfr, acc[s], 0, 0, 0);
        }
        __syncthreads();
    }

    const int col = h * 64 + wave * 16 + mrow;
    #pragma unroll
    for (int s = 0; s < 4; s++)
        #pragma unroll
        for (int reg = 0; reg < 4; reg++) {
            const int rowi = mb * 64 + s * 16 + quad * 4 + reg;
            atomicAdd(&o[(size_t)rowi * 512 + col], acc[s][reg]);
        }
}

// ---------------------------------------------------------------------------
__global__ void build_vt(const float* __restrict__ Vtab, ushort_t* __restrict__ VT)
{
    const int gid = blockIdx.x * 256 + threadIdx.x;  // 8*64*4096
    const int k = gid & 4095;
    const int d = (gid >> 12) & 63;
    const int h = gid >> 18;
    const int s = k >> 1, c = k & 1;
    VT[gid] = f2bf(Vtab[((size_t)(c * S_ + s)) * 512 + h * 64 + d]);
}

// ---------------------------------------------------------------------------
// merged init: feats | act(+actb) | trace | sync tables | zerov
// ---------------------------------------------------------------------------
#define IA_FE 8192
#define IA_AC (IA_FE + 1024)
#define IA_TR (IA_AC + 6400)
#define IA_SY (IA_TR + 9)
#define IA_NB (IA_SY + 1)
__global__ void init_all(const float* __restrict__ emb, const float* __restrict__ Wp,
                         const float* __restrict__ bp, float* __restrict__ f2,
                         const float* __restrict__ sa, float* __restrict__ act,
                         ushort_t* __restrict__ actb,
                         const float* __restrict__ st, float* __restrict__ trace,
                         const float* __restrict__ dec_act, const float* __restrict__ dec_out,
                         int* __restrict__ ijtab, float* __restrict__ r_act,
                         float* __restrict__ r_out, float* __restrict__ sqb_a,
                         float* __restrict__ sqb_o, float* __restrict__ zerov)
{
    const int vb = blockIdx.x, tid = threadIdx.x;
    if (vb < IA_FE) {
        const int gid = vb * 256 + tid;
        const int k = gid & 511;
        const int s = (gid >> 9) & (S_ - 1);
        const int c = gid >> 20;
        const float th = 3.14159265358979323846f * (float)s / (float)(S_ - 1);
        f2[gid] = emb[c * 512 + k] + (-sinf(th)) * Wp[k] + cosf(th) * Wp[512 + k] + bp[k];
    } else if (vb < IA_AC) {
        const int gid = (vb - IA_FE) * 256 + tid;
        const int n = gid & 2047;
        const float v = sa[n];
        act[gid] = v;
        actb[gid] = f2bf(v);
    } else if (vb < IA_TR) {
        const int idx4 = (vb - IA_AC) * 256 + tid;
        ((float4*)trace)[idx4] = ((const float4*)st)[idx4 % 12800];
    } else if (vb < IA_SY) {
        const int p = (vb - IA_TR) * 256 + tid;
        if (p >= REP_) return;
        int i = 0, rem = p;
        while (rem >= NSY_ - i) { rem -= NSY_ - i; i++; }
        ijtab[p] = (i << 16) | (i + rem);
        const float ra = expf(-dec_act[p]);
        const float ro = expf(-dec_out[p]);
        r_act[p] = ra; r_out[p] = ro;
        float ba = 1.f, bo2 = 1.f;
        sqb_a[p] = 1.f;
        sqb_o[p] = 1.f;
        for (int t = 1; t < T_; t++) {
            ba  = ra * ba  + 1.f;
            bo2 = ro * bo2 + 1.f;
            sqb_a[(size_t)t * REP_ + p] = sqrtf(ba);
            sqb_o[(size_t)t * REP_ + p] = sqrtf(bo2);
        }
    } else {
        #pragma unroll
        for (int k = 0; k < 4; k++)
            ((float4*)zerov)[tid * 4 + k] = make_float4(0.f, 0.f, 0.f, 0.f);
    }
}

// ---------------------------------------------------------------------------
// merged 6-way transpose (f32 -> bf16)
// ---------------------------------------------------------------------------
__global__ __launch_bounds__(256) void transpose_all(
    const float* __restrict__ Wk, ushort_t* __restrict__ WkT,
    const float* __restrict__ Wv, ushort_t* __restrict__ WvT,
    const float* __restrict__ Wq, ushort_t* __restrict__ WqT,
    const float* __restrict__ Wo, ushort_t* __restrict__ WoT,
    const float* __restrict__ Ws, ushort_t* __restrict__ WsT,
    const float* __restrict__ Wout, ushort_t* __restrict__ WoutT)
{
    int bid = blockIdx.x;
    const float* in; ushort_t* out; int K, N;
    if      (bid <   256) {              in = Wk;   out = WkT;   K = 512;  N = 512;  }
    else if (bid <   512) { bid -=  256; in = Wv;   out = WvT;   K = 512;  N = 512;  }
    else if (bid <  1552) { bid -=  512; in = Wq;   out = WqT;   K = 2080; N = 512;  }
    else if (bid <  1808) { bid -= 1552; in = Wo;   out = WoT;   K = 512;  N = 512;  }
    else if (bid < 12048) { bid -= 1808; in = Ws;   out = WsT;   K = 2560; N = 4096; }
    else                  { bid -= 12048; in = Wout; out = WoutT; K = 2080; N = 4096; }
    const int bxw = N >> 5;
    const int bx = bid % bxw, by = bid / bxw;
    __shared__ float tile[32][33];
    const int k0 = by * 32, n0 = bx * 32;
    const int tx = threadIdx.x & 31, ty4 = (threadIdx.x >> 5) * 4;
    #pragma unroll
    for (int i = 0; i < 4; i++)
        tile[ty4 + i][tx] = in[(size_t)(k0 + ty4 + i) * N + n0 + tx];
    __syncthreads();
    #pragma unroll
    for (int i = 0; i < 4; i++)
        out[(size_t)(n0 + ty4 + i) * K + k0 + tx] = f2bf(tile[tx][ty4 + i]);
}

__global__ void cast_bf16_kernel(const float* __restrict__ src,
                                 __hip_bfloat16* __restrict__ dst, int n)
{
    const int gid = (blockIdx.x * 256 + threadIdx.x) * 4;
    if (gid >= n) return;
    float4 v = *(const float4*)(src + gid);
    dst[gid + 0] = __float2bfloat16(v.x);
    dst[gid + 1] = __float2bfloat16(v.y);
    dst[gid + 2] = __float2bfloat16(v.z);
    dst[gid + 3] = __float2bfloat16(v.w);
}

// bs2[n] = bs[n] + sum_j bo[j] * Ws[j][n], j in [0,512)
__global__ void bs2_kernel(const float* __restrict__ bs, const float* __restrict__ bo,
                           const float* __restrict__ Ws, float* __restrict__ bs2)
{
    const int n = blockIdx.x * 256 + threadIdx.x;   // 4096
    float acc = bs[n];
    for (int j = 0; j < 512; j++)
        acc += bo[j] * Ws[(size_t)j * 4096 + n];
    bs2[n] = acc;
}

// ---------------------------------------------------------------------------
// prologue-only t=0 action-sync; y==8 block arms qbuf=bq and pre0=bs2
// ---------------------------------------------------------------------------
__global__ void sync_kernel(const float* __restrict__ act,
                            float* __restrict__ alpha,
                            const float* __restrict__ decay,
                            const int t, const int off,
                            ushort_t* __restrict__ sout,
                            float* __restrict__ ib1, const float* __restrict__ bias1, int iN1,
                            float* __restrict__ ib2, const float* __restrict__ bias2, int iN2)
{
    const int b = blockIdx.x;
    const int tid = threadIdx.x;
    if (blockIdx.y == 8) {
        if (ib1)
            for (int n = tid; n < iN1; n += 256)
                ib1[(size_t)b * iN1 + n] = bias1[n];
        if (ib2)
            for (int n = tid; n < iN2; n += 256)
                ib2[(size_t)b * iN2 + n] = bias2[n];
    }
    const int p = blockIdx.y * 256 + tid;
    if (p >= REP_) return;
    int i = 0, rem = p;
    while (rem >= NSY_ - i) { rem -= NSY_ - i; i++; }
    const int j = i + rem;
    const float si = act[(size_t)b * D_MODEL_ + off + i];
    const float sj = act[(size_t)b * D_MODEL_ + off + j];
    const float pair = si * sj;
    const float r = expf(-decay[p]);
    float a;
    if (t == 0) a = pair;
    else        a = r * alpha[(size_t)b * REP_ + p] + pair;
    alpha[(size_t)b * REP_ + p] = a;
    float bta = 1.f;
    for (int k = 0; k < t; k++) bta = r * bta + 1.f;
    sout[(size_t)b * REP_ + p] = f2bf(a / sqrtf(bta));
}

// ---------------------------------------------------------------------------
// state/trace/act, TT = compile-time iteration -> circular trace with
// compile-time slot offsets (vectorizable). Logical order of x[] identical to
// the shift-register version -> bit-identical sums. Epilogues:
//   half==0: sync_out(TT) + predt=bout ; half==1: sync_act(TT+1) + qbuf=bq.
// ---------------------------------------------------------------------------
template<int TT>
__global__ __launch_bounds__(512, 2) void st_kernel(
    const float* __restrict__ pre,    // (B,4096)
    const float* __restrict__ g,
    const float* __restrict__ bt,
    float* __restrict__ trace,        // (B,2048,25) circular
    const float* __restrict__ ln_g,
    const float* __restrict__ ln_b,
    const float* __restrict__ Wn,
    const float* __restrict__ bn,
    const float* __restrict__ temp,
    ushort_t* __restrict__ actb,      // (B,2048) bf16
    const int* __restrict__ ijtab,
    const float* __restrict__ r_out,
    const float* __restrict__ sqb_out,
    float* __restrict__ a_o,
    ushort_t* __restrict__ s_outb,
    const float* __restrict__ bout,
    float* __restrict__ predt,
    const float* __restrict__ r_act,
    const float* __restrict__ sqb_act,
    float* __restrict__ a_a,
    ushort_t* __restrict__ s_actb,
    const float* __restrict__ bq,
    float* __restrict__ qbuf)
{
    const int b = blockIdx.x >> 1, half = blockIdx.x & 1;
    const int tid = threadIdx.x;          // 0..511
    __shared__ float v[D_MODEL_];
    __shared__ float r1[512], r2[512];
    __shared__ float sh_sync[64];
    float s1 = 0.f, s2 = 0.f;
    #pragma unroll
    for (int i = 0; i < 4; i++) {
        const int dd = tid + i * 512;
        const float g1 = pre[(size_t)b * 4096 + dd];
        const float g2 = pre[(size_t)b * 4096 + 2048 + dd];
        const float val = g1 * (1.f / (1.f + expf(-g2)));
        v[dd] = val; s1 += val; s2 += val * val;
    }
    r1[tid] = s1; r2[tid] = s2; __syncthreads();
    for (int off = 256; off > 0; off >>= 1) {
        if (tid < off) { r1[tid] += r1[tid + off]; r2[tid] += r2[tid + off]; }
        __syncthreads();
    }
    const float mu = r1[0] * (1.f / D_MODEL_);
    const float var = fmaxf(r2[0] * (1.f / D_MODEL_) - mu * mu, 0.f);
    const float sinv = 1.f / sqrtf(var + 1e-5f);
    const float tval = temp[0];

    #pragma unroll
    for (int i = 0; i < 2; i++) {
        const int n = half * 1024 + i * 512 + tid;
        const float sval = (v[n] - mu) * sinv * g[n] + bt[n];
        const int gid = b * 2048 + n;
        float* tr = trace + (size_t)gid * M_;
        float x[M_];
        #pragma unroll
        for (int m = 0; m < M_ - 1; m++) {
            int slot = TT + 1 + m;            // compile-time after unroll
            if (slot >= M_) slot -= M_;
            x[m] = tr[slot];
        }
        x[M_ - 1] = sval;
        tr[TT] = sval;                        // single write (circular head)
        float t1 = 0.f, t2 = 0.f;
        #pragma unroll
        for (int m = 0; m < M_; m++) { t1 += x[m]; t2 += x[m] * x[m]; }
        const float tmu = t1 * (1.f / M_);
        const float tvar = fmaxf(t2 * (1.f / M_) - tmu * tmu, 0.f);
        const float tinv = 1.f / sqrtf(tvar + 1e-5f);
        float y0 = bn[n * 2 + 0], y1 = bn[n * 2 + 1];
        #pragma unroll
        for (int m = 0; m < M_; m++) {
            const float xn = (x[m] - tmu) * tinv * ln_g[m] + ln_b[m];
            y0 += xn * Wn[(size_t)(m * 2 + 0) * D_MODEL_ + n];
            y1 += xn * Wn[(size_t)(m * 2 + 1) * D_MODEL_ + n];
        }
        const float a = y0 * (1.f / (1.f + expf(-y1))) / tval;
        actb[gid] = f2bf(a);
        if (half == 0) {
            if (i == 0 && tid < 64) sh_sync[tid] = a;            // act[b, 0..63]
        } else {
            if (i == 1 && tid >= 448) sh_sync[tid - 448] = a;    // act[b, 1984..2047]
        }
    }
    __syncthreads();

    if (half == 0) {
        for (int p = tid; p < REP_; p += 512) {
            const int ij = ijtab[p];
            const float pair = sh_sync[ij >> 16] * sh_sync[ij & 0xffff];
            const float r = r_out[p];
            float a2;
            if (TT == 0) a2 = pair;
            else         a2 = r * a_o[(size_t)b * REP_ + p] + pair;
            a_o[(size_t)b * REP_ + p] = a2;
            s_outb[(size_t)b * REP_ + p] = f2bf(a2 / sqb_out[(size_t)TT * REP_ + p]);
        }
        const float4* b4 = (const float4*)bout;
        float4* pd = (float4*)(predt + (size_t)b * 4096);
        for (int idx = tid; idx < 1024; idx += 512) pd[idx] = b4[idx];
    } else if (TT < T_ - 1) {
        for (int p = tid; p < REP_; p += 512) {
            const int ij = ijtab[p];
            const float pair = sh_sync[ij >> 16] * sh_sync[ij & 0xffff];
            const float r = r_act[p];
            float a2 = r * a_a[(size_t)b * REP_ + p] + pair;    // TT+1 >= 1
            a_a[(size_t)b * REP_ + p] = a2;
            s_actb[(size_t)b * REP_ + p] = f2bf(a2 / sqb_act[(size_t)(TT + 1) * REP_ + p]);
        }
        const float4* b4 = (const float4*)bq;
        float4* qb = (float4*)(qbuf + (size_t)b * 512);
        if (tid < 128) qb[tid] = b4[tid];
    }
}

// ---------------------------------------------------------------------------
__global__ __launch_bounds__(256) void ent_all_kernel(
    const float* __restrict__ predst,  // (T, B*4096)
    float* __restrict__ certbf)        // (T, B*2)
{
    const int t = blockIdx.x >> 7;
    const int b = blockIdx.x & 127;
    const int tid = threadIdx.x;
    __shared__ float red[256];
    const float* pr = predst + (size_t)t * PRED_N + (size_t)b * 4096;
    float sum = 0.f;
    #pragma unroll
    for (int i = 0; i < 8; i++) {
        const int s = tid + i * 256;
        const float l0 = pr[2 * s], l1 = pr[2 * s + 1];
        const float mm = fmaxf(l0, l1);
        const float z0 = expf(l0 - mm), z1 = expf(l1 - mm);
        const float Z = z0 + z1;
        const float lz = logf(Z);
        const float p0 = z0 / Z, p1 = z1 / Z;
        const float lp0 = (l0 - mm) - lz, lp1 = (l1 - mm) - lz;
        sum += -(p0 * lp0 + p1 * lp1) * 1.4426950408889634f;
    }
    red[tid] = sum; __syncthreads();
    for (int off = 128; off > 0; off >>= 1) {
        if (tid < off) red[tid] += red[tid + off];
        __syncthreads();
    }
    if (tid == 0) {
        const float ne = red[0] * (1.f / S_);
        certbf[(size_t)t * B_ * 2 + b * 2 + 0] = ne;
        certbf[(size_t)t * B_ * 2 + b * 2 + 1] = 1.f - ne;
    }
}

// ---------------------------------------------------------------------------
__global__ __launch_bounds__(256) void finalize_kernel(
    const float* __restrict__ predstage,  // (T, B*4096)
    const float* __restrict__ certbuf,    // (T, B*2)
    float* __restrict__ dout)
{
    __shared__ float tile[T_][1024];
    const int tid = threadIdx.x;
    const int row0 = blockIdx.x * 1024;
    #pragma unroll
    for (int t = 0; t < T_; t++) {
        float4 v = *(const float4*)(predstage + (size_t)t * PRED_N + row0 + tid * 4);
        tile[t][tid * 4 + 0] = v.x; tile[t][tid * 4 + 1] = v.y;
        tile[t][tid * 4 + 2] = v.z; tile[t][tid * 4 + 3] = v.w;
    }
    __syncthreads();
    float buf[40];
    #pragma unroll
    for (int r = 0; r < 4; r++)
        #pragma unroll
        for (int t = 0; t < T_; t++)
            buf[r * 10 + t] = tile[t][tid * 4 + r];
    float* dst = dout + (size_t)(row0 + tid * 4) * T_;
    #pragma unroll
    for (int k = 0; k < 10; k++)
        *(float4*)(dst + k * 4) = make_float4(buf[4*k], buf[4*k+1], buf[4*k+2], buf[4*k+3]);

    if (blockIdx.x == 0 && tid < B_) {
        const int b = tid;
        const size_t base = (size_t)PRED_N * T_;
        #pragma unroll
        for (int t = 0; t < T_; t++) {
            dout[base + (size_t)(b * 2 + 0) * T_ + t] = certbuf[t * B_ * 2 + b * 2 + 0];
            dout[base + (size_t)(b * 2 + 1) * T_ + t] = certbuf[t * B_ * 2 + b * 2 + 1];
        }
    }
}

// ===========================================================================
extern "C" void kernel_launch(void* const* d_in, const int* in_sizes, int n_in,
                              void* d_out, int out_size, void* d_ws, size_t ws_size,
                              hipStream_t stream)
{
    const int*   tokens    = (const int*)  d_in[0];
    const float* emb       = (const float*)d_in[1];
    const float* W_pos     = (const float*)d_in[2];
    const float* b_pos     = (const float*)d_in[3];
    const float* Wq        = (const float*)d_in[4];
    const float* bq        = (const float*)d_in[5];
    const float* Wk        = (const float*)d_in[6];
    const float* bk        = (const float*)d_in[7];
    const float* Wv        = (const float*)d_in[8];
    const float* bv        = (const float*)d_in[9];
    const float* Wo        = (const float*)d_in[10];
    const float* bo        = (const float*)d_in[11];
    const float* Ws        = (const float*)d_in[12];
    const float* bs        = (const float*)d_in[13];
    const float* ln_s_g    = (const float*)d_in[14];
    const float* ln_s_b    = (const float*)d_in[15];
    const float* ln_n_g    = (const float*)d_in[16];
    const float* ln_n_b    = (const float*)d_in[17];
    const float* Wn        = (const float*)d_in[18];
    const float* bn        = (const float*)d_in[19];
    const float* temp      = (const float*)d_in[20];
    const float* Wout      = (const float*)d_in[21];
    const float* bout      = (const float*)d_in[22];
    const float* start_act = (const float*)d_in[23];
    const float* start_tr  = (const float*)d_in[24];
    const float* dec_act   = (const float*)d_in[25];
    const float* dec_out   = (const float*)d_in[26];
    float* out = (float*)d_out;
    float* w = (float*)d_ws;

    // workspace layout (floats)
    size_t off = 0;
    float* f2     = w + off; off += (size_t)2 * S_ * 512;
    float* Ktab   = w + off; off += (size_t)2 * S_ * 512;
    float* Vtab   = w + off; off += (size_t)2 * S_ * 512;
    float* act    = w + off; off += (size_t)B_ * D_MODEL_;
    float* a_a    = w + off; off += (size_t)B_ * REP_;
    float* a_o    = w + off; off += (size_t)B_ * REP_;
    float* qbuf   = w + off; off += (size_t)B_ * 512;
    float* o_attn = w + off; off += (size_t)B_ * 512;
    float* pre0   = w + off; off += (size_t)B_ * 4096;
    float* pre1   = w + off; off += (size_t)B_ * 4096;
    float* trace  = w + off; off += (size_t)B_ * D_MODEL_ * M_;
    float* scbuf  = w + off; off += (size_t)16 * 128 * S_;
    float* predst = w + off; off += (size_t)T_ * PRED_N;
    float* certbf = w + off; off += (size_t)T_ * B_ * 2;
    float* Wcomb32= w + off; off += (size_t)4096 * 512;
    float* bs2    = w + off; off += 4096;
    float* zerov  = w + off; off += 4096;
    ushort_t* s_actb = (ushort_t*)(w + off); off += (size_t)B_ * REP_ / 2;
    ushort_t* s_outb = (ushort_t*)(w + off); off += (size_t)B_ * REP_ / 2;
    ushort_t* actb   = (ushort_t*)(w + off); off += (size_t)B_ * D_MODEL_ / 2;
    __hip_bfloat16* Kb = (__hip_bfloat16*)(w + off); off += (size_t)S_ * 512;
    ushort_t* Pbuf  = (ushort_t*)(w + off); off += (size_t)8 * 128 * 4096 / 2;
    ushort_t* VT    = (ushort_t*)(w + off); off += (size_t)8 * 64 * 4096 / 2;
    ushort_t* WkT   = (ushort_t*)(w + off); off += (size_t)512 * 512 / 2;
    ushort_t* WvT   = (ushort_t*)(w + off); off += (size_t)512 * 512 / 2;
    ushort_t* WqT   = (ushort_t*)(w + off); off += (size_t)512 * REP_ / 2;
    ushort_t* WoT   = (ushort_t*)(w + off); off += (size_t)512 * 512 / 2;
    ushort_t* WsT   = (ushort_t*)(w + off); off += (size_t)4096 * 2560 / 2;
    ushort_t* WoutT = (ushort_t*)(w + off); off += (size_t)4096 * REP_ / 2;
    ushort_t* WoC   = (ushort_t*)(w + off); off += (size_t)512 * 512 / 2;
    ushort_t* WcombTb=(ushort_t*)(w + off); off += (size_t)4096 * 512 / 2;
    int*   ijtab  = (int*)(w + off); off += REP_;
    float* r_actT = w + off; off += REP_;
    float* r_outT = w + off; off += REP_;
    float* sqb_a  = w + off; off += (size_t)T_ * REP_;
    float* sqb_o  = w + off; off += (size_t)T_ * REP_;

    // ---- prologue ----
    init_all<<<IA_NB, 256, 0, stream>>>(
        emb, W_pos, b_pos, f2, start_act, act, actb, start_tr, trace,
        dec_act, dec_out, ijtab, r_actT, r_outT, sqb_a, sqb_o, zerov);
    transpose_all<<<20368, 256, 0, stream>>>(
        Wk, WkT, Wv, WvT, Wq, WqT, Wo, WoT, Ws, WsT, Wout, WoutT);
    gemm_bf16<<<dim3(4, 64, 1), 256, 0, stream>>>(
        f2, 512, WkT, 512, bk, Ktab, 512, 2 * S_, 512, 512, 512);
    gemm_bf16<<<dim3(4, 64, 1), 256, 0, stream>>>(
        f2, 512, WvT, 512, bv, Vtab, 512, 2 * S_, 512, 512, 512);
    cast_bf16_kernel<<<(2 * S_ * 512 / 4) / 256, 256, 0, stream>>>(Ktab, Kb, 2 * S_ * 512);
    build_vt<<<(8 * 64 * 4096) / 256, 256, 0, stream>>>(Vtab, VT);

    // Wcomb = Wo @ Ws_top : WoC = bf16(Wo) ; Wcomb32[n][k] = sum_j WsT[n][j]*WoC[k][j]
    cast_bf16_kernel<<<(512 * 512 / 4) / 256, 256, 0, stream>>>(
        Wo, (__hip_bfloat16*)WoC, 512 * 512);
    gemm_bb<<<dim3(4, 64, 1), 256, 0, stream>>>(
        WsT, 2560, WoC, 512, zerov, Wcomb32, 512, 4096, 512, 512, 512);
    cast_bf16_kernel<<<(4096 * 512 / 4) / 256, 256, 0, stream>>>(
        Wcomb32, (__hip_bfloat16*)WcombTb, 4096 * 512);
    bs2_kernel<<<16, 256, 0, stream>>>(bs, bo, Ws, bs2);

    // t=0 action-sync; arms qbuf=bq and pre0=bs2
    sync_kernel<<<dim3(B_, 9), 256, 0, stream>>>(
        act, a_a, dec_act, 0, D_MODEL_ - NSY_, s_actb,
        qbuf, bq, 512, pre0, bs2, 4096);
    // Ws_act(0): actb @ WsT[:,k>=512] -> pre0 (atomic)
    gemm_bb<<<dim3(32, 2, 8), 256, 0, stream>>>(
        actb, 2048, WsT + 512, 2560, zerov, pre0, 4096, B_, 4096, 2048, 256);
    // q(0) (atomic, qbuf armed with bq)
    gemm_bb<<<dim3(4, 2, 13), 256, 0, stream>>>(
        s_actb, REP_, WqT, REP_, zerov, qbuf, 512, B_, 512, REP_, 160);

    // ---- T iterations (6 launches each) ----
    #define ST_ARGS(PC, PT) \
        PC, ln_s_g, ln_s_b, trace, ln_n_g, ln_n_b, Wn, bn, temp, actb, \
        ijtab, r_outT, sqb_o, a_o, s_outb, bout, PT, \
        r_actT, sqb_a, a_a, s_actb, bq, qbuf

    for (int t = 0; t < T_; t++) {
        float* pre_cur = (t & 1) ? pre1 : pre0;
        float* pre_nxt = (t & 1) ? pre0 : pre1;
        float* predt = predst + (size_t)t * PRED_N;

        gemm_qk<<<dim3(S_ / 128, 2, 16), 256, 0, stream>>>(
            qbuf, (const ushort_t*)Kb, scbuf);
        // softmax + arms (pre_nxt=bs2, o_attn=0)
        attn_soft<<<B_ * H_, 256, 0, stream>>>(
            scbuf, tokens, Pbuf, o_attn, bs2, pre_nxt);
        gemm_pv<<<dim3(2, 8, 8), 256, 0, stream>>>(Pbuf, VT, o_attn);

        // fused Wo+Ws_top: pre_cur += o_attn @ Wcomb (K=512, atomic)
        gemm_bf16<<<dim3(32, 2, 4), 256, 0, stream>>>(
            o_attn, 512, WcombTb, 512, bs2, pre_cur, 4096, B_, 4096, 512, 128);

        // state/trace/act + sync_out(t) + predt=bout + sync_act(t+1) + qbuf=bq
        switch (t) {
            case 0: st_kernel<0><<<B_ * 2, 512, 0, stream>>>(ST_ARGS(pre_cur, predt)); break;
            case 1: st_kernel<1><<<B_ * 2, 512, 0, stream>>>(ST_ARGS(pre_cur, predt)); break;
            case 2: st_kernel<2><<<B_ * 2, 512, 0, stream>>>(ST_ARGS(pre_cur, predt)); break;
            case 3: st_kernel<3><<<B_ * 2, 512, 0, stream>>>(ST_ARGS(pre_cur, predt)); break;
            case 4: st_kernel<4><<<B_ * 2, 512, 0, stream>>>(ST_ARGS(pre_cur, predt)); break;
            case 5: st_kernel<5><<<B_ * 2, 512, 0, stream>>>(ST_ARGS(pre_cur, predt)); break;
            case 6: st_kernel<6><<<B_ * 2, 512, 0, stream>>>(ST_ARGS(pre_cur, predt)); break;
            case 7: st_kernel<7><<<B_ * 2, 512, 0, stream>>>(ST_ARGS(pre_cur, predt)); break;
            case 8: st_kernel<8><<<B_ * 2, 512, 0, stream>>>(ST_ARGS(pre_cur, predt)); break;
            case 9: st_kernel<9><<<B_ * 2, 512, 0, stream>>>(ST_ARGS(pre_cur, predt)); break;
        }

        // merged tail: Wout(t) + q(t+1) + Ws_act(t+1)
        const int nblk = (t < T_ - 1) ? 936 : 320;
        triple_kernel<<<nblk, 256, 0, stream>>>(
            s_outb, WoutT, predt, s_actb, WqT, qbuf, actb, WsT, pre_nxt);
    }

    // batched entropy + coalesced output pass
    ent_all_kernel<<<T_ * B_, 256, 0, stream>>>(predst, certbf);
    finalize_kernel<<<PRED_N / 1024, 256, 0, stream>>>(predst, certbf, out);
}

// Round 6
// 1112.902 us; speedup vs baseline: 3.0947x; 1.0400x over previous
//
#include <hip/hip_runtime.h>
#include <hip/hip_bf16.h>
#include <math.h>

#define B_ 128
#define S_ 2048
#define D_IN_ 512
#define D_MODEL_ 2048
#define M_ 25
#define NSY_ 64
#define H_ 8
#define T_ 10
#define REP_ 2080
#define DH_ 64
#define PRED_N (B_ * 4096)

typedef unsigned short ushort_t;
typedef __bf16 bf16x8 __attribute__((ext_vector_type(8)));
typedef float f32x4 __attribute__((ext_vector_type(4)));
typedef unsigned short us8 __attribute__((ext_vector_type(8)));
typedef unsigned short us4 __attribute__((ext_vector_type(4)));

__device__ __forceinline__ ushort_t f2bf(float f) {
    __hip_bfloat16 h = __float2bfloat16(f);
    return *(ushort_t*)&h;
}

// ---------------------------------------------------------------------------
// MFMA bf16 GEMM, f32 A (cast during staging). Z>1 -> atomicAdd epilogue.
// Used in-loop for the fused Wo+Ws_top GEMM (o_attn @ Wcomb -> pre, atomic).
// ---------------------------------------------------------------------------
__global__ __launch_bounds__(256) void gemm_bf16(
    const float* __restrict__ A, int lda,
    const ushort_t* __restrict__ Bt, int ldb,
    const float* __restrict__ bias,
    float* __restrict__ C, int ldc,
    int M, int N, int K, int kchunk)
{
    const int nb = blockIdx.x, mb = blockIdx.y, zb = blockIdx.z;
    const int k0 = zb * kchunk;
    const int k1 = min(K, k0 + kchunk);
    __shared__ ushort_t As[64][40];
    __shared__ ushort_t Bs[128][40];

    const int tid  = threadIdx.x;
    const int wave = tid >> 6;
    const int lane = tid & 63;
    const int quad = lane >> 4;
    const int mrow = lane & 15;

    f32x4 acc[4][2];
    #pragma unroll
    for (int s = 0; s < 4; s++)
        #pragma unroll
        for (int u = 0; u < 2; u++)
            acc[s][u] = (f32x4){0.f, 0.f, 0.f, 0.f};

    const int arow = tid >> 2, akc = (tid & 3) * 8;
    const int brow = tid >> 1, bkc = (tid & 1) * 16;

    for (int kk0 = k0; kk0 < k1; kk0 += 32) {
        {
            const float* ap = A + (size_t)(mb * 64 + arow) * lda + kk0 + akc;
            float4 v0 = *(const float4*)ap;
            float4 v1 = *(const float4*)(ap + 4);
            us8 w = { f2bf(v0.x), f2bf(v0.y), f2bf(v0.z), f2bf(v0.w),
                      f2bf(v1.x), f2bf(v1.y), f2bf(v1.z), f2bf(v1.w) };
            *(us8*)&As[arow][akc] = w;
        }
        {
            const ushort_t* bp = Bt + (size_t)(nb * 128 + brow) * ldb + kk0 + bkc;
            *(us8*)&Bs[brow][bkc]     = *(const us8*)bp;
            *(us8*)&Bs[brow][bkc + 8] = *(const us8*)(bp + 8);
        }
        __syncthreads();

        bf16x8 af[4], bfr[2];
        #pragma unroll
        for (int s = 0; s < 4; s++)
            af[s] = *(const bf16x8*)&As[s * 16 + mrow][quad * 8];
        #pragma unroll
        for (int u = 0; u < 2; u++)
            bfr[u] = *(const bf16x8*)&Bs[wave * 32 + u * 16 + mrow][quad * 8];
        #pragma unroll
        for (int s = 0; s < 4; s++)
            #pragma unroll
            for (int u = 0; u < 2; u++)
                acc[s][u] = __builtin_amdgcn_mfma_f32_16x16x32_bf16(
                    af[s], bfr[u], acc[s][u], 0, 0, 0);
        __syncthreads();
    }

    if (gridDim.z == 1) {
        #pragma unroll
        for (int s = 0; s < 4; s++)
            #pragma unroll
            for (int u = 0; u < 2; u++) {
                const int col = nb * 128 + wave * 32 + u * 16 + mrow;
                #pragma unroll
                for (int reg = 0; reg < 4; reg++) {
                    const int row = mb * 64 + s * 16 + quad * 4 + reg;
                    C[(size_t)row * ldc + col] = acc[s][u][reg] + bias[col];
                }
            }
    } else {
        #pragma unroll
        for (int s = 0; s < 4; s++)
            #pragma unroll
            for (int u = 0; u < 2; u++) {
                const int col = nb * 128 + wave * 32 + u * 16 + mrow;
                #pragma unroll
                for (int reg = 0; reg < 4; reg++) {
                    const int row = mb * 64 + s * 16 + quad * 4 + reg;
                    atomicAdd(&C[(size_t)row * ldc + col], acc[s][u][reg]);
                }
            }
    }
}

// ---------------------------------------------------------------------------
// Prologue 3-way GEMM in one launch: grid (4, 64, 3).
//  zs=0: Ktab = f2 @ WkT^T + bk      (A f32, lda 512)
//  zs=1: Vtab = f2 @ WvT^T + bv      (A f32, lda 512)
//  zs=2: Wcomb32 = WsT @ WoC^T       (A bf16, lda 2560, bias zerov)
// All M=4096, N=512, K=512, direct store, ldc=512, ldb=512.
// ---------------------------------------------------------------------------
__global__ __launch_bounds__(256) void gemm3_kernel(
    const float* __restrict__ f2,
    const ushort_t* __restrict__ WkT, const float* __restrict__ bk, float* __restrict__ Ktab,
    const ushort_t* __restrict__ WvT, const float* __restrict__ bv, float* __restrict__ Vtab,
    const ushort_t* __restrict__ WsT, const ushort_t* __restrict__ WoC,
    const float* __restrict__ zerov, float* __restrict__ Wcomb32)
{
    const int nb = blockIdx.x, mb = blockIdx.y, zs = blockIdx.z;
    const ushort_t* Bt = (zs == 0) ? WkT : (zs == 1) ? WvT : WoC;
    const float* bias  = (zs == 0) ? bk  : (zs == 1) ? bv  : zerov;
    float* C           = (zs == 0) ? Ktab : (zs == 1) ? Vtab : Wcomb32;

    __shared__ ushort_t As[64][40];
    __shared__ ushort_t Bs[128][40];

    const int tid  = threadIdx.x;
    const int wave = tid >> 6;
    const int lane = tid & 63;
    const int quad = lane >> 4;
    const int mrow = lane & 15;

    f32x4 acc[4][2];
    #pragma unroll
    for (int s = 0; s < 4; s++)
        #pragma unroll
        for (int u = 0; u < 2; u++)
            acc[s][u] = (f32x4){0.f, 0.f, 0.f, 0.f};

    const int arow = tid >> 2, akc = (tid & 3) * 8;
    const int brow = tid >> 1, bkc = (tid & 1) * 16;

    for (int kk0 = 0; kk0 < 512; kk0 += 32) {
        if (zs < 2) {
            const float* ap = f2 + (size_t)(mb * 64 + arow) * 512 + kk0 + akc;
            float4 v0 = *(const float4*)ap;
            float4 v1 = *(const float4*)(ap + 4);
            us8 w = { f2bf(v0.x), f2bf(v0.y), f2bf(v0.z), f2bf(v0.w),
                      f2bf(v1.x), f2bf(v1.y), f2bf(v1.z), f2bf(v1.w) };
            *(us8*)&As[arow][akc] = w;
        } else {
            const ushort_t* ap = WsT + (size_t)(mb * 64 + arow) * 2560 + kk0 + akc;
            *(us8*)&As[arow][akc] = *(const us8*)ap;
        }
        {
            const ushort_t* bp = Bt + (size_t)(nb * 128 + brow) * 512 + kk0 + bkc;
            *(us8*)&Bs[brow][bkc]     = *(const us8*)bp;
            *(us8*)&Bs[brow][bkc + 8] = *(const us8*)(bp + 8);
        }
        __syncthreads();

        bf16x8 af[4], bfr[2];
        #pragma unroll
        for (int s = 0; s < 4; s++)
            af[s] = *(const bf16x8*)&As[s * 16 + mrow][quad * 8];
        #pragma unroll
        for (int u = 0; u < 2; u++)
            bfr[u] = *(const bf16x8*)&Bs[wave * 32 + u * 16 + mrow][quad * 8];
        #pragma unroll
        for (int s = 0; s < 4; s++)
            #pragma unroll
            for (int u = 0; u < 2; u++)
                acc[s][u] = __builtin_amdgcn_mfma_f32_16x16x32_bf16(
                    af[s], bfr[u], acc[s][u], 0, 0, 0);
        __syncthreads();
    }

    #pragma unroll
    for (int s = 0; s < 4; s++)
        #pragma unroll
        for (int u = 0; u < 2; u++) {
            const int col = nb * 128 + wave * 32 + u * 16 + mrow;
            #pragma unroll
            for (int reg = 0; reg < 4; reg++) {
                const int row = mb * 64 + s * 16 + quad * 4 + reg;
                C[(size_t)row * 512 + col] = acc[s][u][reg] + bias[col];
            }
        }
}

// ---------------------------------------------------------------------------
// Shared 64x128 bf16 GEMM tile (atomic epilogue) for triple/dual kernels.
// ---------------------------------------------------------------------------
__device__ __forceinline__ void g_tile128(
    const ushort_t* Ap, int lda, const ushort_t* Bt, int ldb,
    float* C, int ldc, int nb, int mb, int k0, int k1, char* smem, int tid)
{
    ushort_t (*As)[40] = (ushort_t(*)[40])smem;
    ushort_t (*Bs)[40] = (ushort_t(*)[40])(smem + 64 * 40 * 2);
    const int wave = tid >> 6;
    const int lane = tid & 63;
    const int quad = lane >> 4;
    const int mrow = lane & 15;

    f32x4 acc[4][2];
    #pragma unroll
    for (int s = 0; s < 4; s++)
        #pragma unroll
        for (int u = 0; u < 2; u++)
            acc[s][u] = (f32x4){0.f, 0.f, 0.f, 0.f};

    const int arow = tid >> 2, akc = (tid & 3) * 8;
    const int brow = tid >> 1, bkc = (tid & 1) * 16;

    for (int kk0 = k0; kk0 < k1; kk0 += 32) {
        {
            const ushort_t* ap = Ap + (size_t)(mb * 64 + arow) * lda + kk0 + akc;
            *(us8*)&As[arow][akc] = *(const us8*)ap;
        }
        {
            const ushort_t* bp = Bt + (size_t)(nb * 128 + brow) * ldb + kk0 + bkc;
            *(us8*)&Bs[brow][bkc]     = *(const us8*)bp;
            *(us8*)&Bs[brow][bkc + 8] = *(const us8*)(bp + 8);
        }
        __syncthreads();

        bf16x8 af[4], bfr[2];
        #pragma unroll
        for (int s = 0; s < 4; s++)
            af[s] = *(const bf16x8*)&As[s * 16 + mrow][quad * 8];
        #pragma unroll
        for (int u = 0; u < 2; u++)
            bfr[u] = *(const bf16x8*)&Bs[wave * 32 + u * 16 + mrow][quad * 8];
        #pragma unroll
        for (int s = 0; s < 4; s++)
            #pragma unroll
            for (int u = 0; u < 2; u++)
                acc[s][u] = __builtin_amdgcn_mfma_f32_16x16x32_bf16(
                    af[s], bfr[u], acc[s][u], 0, 0, 0);
        __syncthreads();
    }

    #pragma unroll
    for (int s = 0; s < 4; s++)
        #pragma unroll
        for (int u = 0; u < 2; u++) {
            const int col = nb * 128 + wave * 32 + u * 16 + mrow;
            #pragma unroll
            for (int reg = 0; reg < 4; reg++) {
                const int row = mb * 64 + s * 16 + quad * 4 + reg;
                atomicAdd(&C[(size_t)row * ldc + col], acc[s][u][reg]);
            }
        }
}

// ---------------------------------------------------------------------------
// Merged tail: Wout(t) [0,320) + q(t+1) [320,424) + Ws_act(t+1) [424,936)
// ---------------------------------------------------------------------------
__global__ __launch_bounds__(256) void triple_kernel(
    const ushort_t* __restrict__ s_outb, const ushort_t* __restrict__ WoutT,
    float* __restrict__ predt,
    const ushort_t* __restrict__ s_actb, const ushort_t* __restrict__ WqT,
    float* __restrict__ qbuf,
    const ushort_t* __restrict__ actb, const ushort_t* __restrict__ WsT,
    float* __restrict__ pre_nxt)
{
    __shared__ __align__(16) char smem[15360];
    const int vb = blockIdx.x, tid = threadIdx.x;
    if (vb < 320) {
        const int nb = vb & 31, mb = (vb >> 5) & 1, zb = vb >> 6;
        const int k0 = zb * 416;
        g_tile128(s_outb, REP_, WoutT, REP_, predt, 4096,
                  nb, mb, k0, min(REP_, k0 + 416), smem, tid);
    } else if (vb < 424) {
        const int v2 = vb - 320;
        const int nb = v2 & 3, mb = (v2 >> 2) & 1, zb = v2 >> 3;
        const int k0 = zb * 160;
        g_tile128(s_actb, REP_, WqT, REP_, qbuf, 512,
                  nb, mb, k0, min(REP_, k0 + 160), smem, tid);
    } else {
        const int v3 = vb - 424;
        const int nb = v3 & 31, mb = (v3 >> 5) & 1, zb = v3 >> 6;
        const int k0 = zb * 256;
        g_tile128(actb, 2048, WsT + 512, 2560, pre_nxt, 4096,
                  nb, mb, k0, k0 + 256, smem, tid);
    }
}

// ---------------------------------------------------------------------------
// Prologue dual: Ws_act(0) [0,512) + q(0) [512,616). Targets pre-armed.
// ---------------------------------------------------------------------------
__global__ __launch_bounds__(256) void dual0_kernel(
    const ushort_t* __restrict__ actb, const ushort_t* __restrict__ WsT,
    float* __restrict__ pre0,
    const ushort_t* __restrict__ s_actb, const ushort_t* __restrict__ WqT,
    float* __restrict__ qbuf)
{
    __shared__ __align__(16) char smem[15360];
    const int vb = blockIdx.x, tid = threadIdx.x;
    if (vb < 512) {
        const int nb = vb & 31, mb = (vb >> 5) & 1, zb = vb >> 6;
        const int k0 = zb * 256;
        g_tile128(actb, 2048, WsT + 512, 2560, pre0, 4096,
                  nb, mb, k0, k0 + 256, smem, tid);
    } else {
        const int v2 = vb - 512;
        const int nb = v2 & 3, mb = (v2 >> 2) & 1, zb = v2 >> 3;
        const int k0 = zb * 160;
        g_tile128(s_actb, REP_, WqT, REP_, qbuf, 512,
                  nb, mb, k0, min(REP_, k0 + 160), smem, tid);
    }
}

// ---------------------------------------------------------------------------
// QK scores with token-selected write: both c-blocks compute dense scores but
// write only entries whose token matches c -> disjoint writes into half-size
// scsel[(h*128+b)*S + s]. grid (16, 2, 16), z = c*8+h.
// ---------------------------------------------------------------------------
__global__ __launch_bounds__(256) void gemm_qk_sel(
    const float* __restrict__ q,
    const ushort_t* __restrict__ Kb,
    const unsigned* __restrict__ tokbit,   // (B, 64) bitmask of tokens
    float* __restrict__ scsel)             // (8,128,2048)
{
    const int nb = blockIdx.x, mb = blockIdx.y, z = blockIdx.z;
    const int c = z >> 3, h = z & 7;
    __shared__ ushort_t As[64][40];
    __shared__ ushort_t Bs[128][40];

    const int tid  = threadIdx.x;
    const int wave = tid >> 6;
    const int lane = tid & 63;
    const int quad = lane >> 4;
    const int mrow = lane & 15;

    f32x4 acc[4][2];
    #pragma unroll
    for (int s = 0; s < 4; s++)
        #pragma unroll
        for (int u = 0; u < 2; u++)
            acc[s][u] = (f32x4){0.f, 0.f, 0.f, 0.f};

    const int arow = tid >> 2, akc = (tid & 3) * 8;
    const int brow = tid >> 1, bkc = (tid & 1) * 16;
    const float* Abase = q + (size_t)h * 64;
    const ushort_t* Bbase = Kb + (size_t)c * S_ * 512 + h * 64;

    #pragma unroll
    for (int kk0 = 0; kk0 < 64; kk0 += 32) {
        {
            const float* ap = Abase + (size_t)(mb * 64 + arow) * 512 + kk0 + akc;
            float4 v0 = *(const float4*)ap;
            float4 v1 = *(const float4*)(ap + 4);
            us8 w = { f2bf(v0.x), f2bf(v0.y), f2bf(v0.z), f2bf(v0.w),
                      f2bf(v1.x), f2bf(v1.y), f2bf(v1.z), f2bf(v1.w) };
            *(us8*)&As[arow][akc] = w;
        }
        {
            const ushort_t* bp = Bbase + (size_t)(nb * 128 + brow) * 512 + kk0 + bkc;
            *(us8*)&Bs[brow][bkc]     = *(const us8*)bp;
            *(us8*)&Bs[brow][bkc + 8] = *(const us8*)(bp + 8);
        }
        __syncthreads();

        bf16x8 af[4], bfr[2];
        #pragma unroll
        for (int s = 0; s < 4; s++)
            af[s] = *(const bf16x8*)&As[s * 16 + mrow][quad * 8];
        #pragma unroll
        for (int u = 0; u < 2; u++)
            bfr[u] = *(const bf16x8*)&Bs[wave * 32 + u * 16 + mrow][quad * 8];
        #pragma unroll
        for (int s = 0; s < 4; s++)
            #pragma unroll
            for (int u = 0; u < 2; u++)
                acc[s][u] = __builtin_amdgcn_mfma_f32_16x16x32_bf16(
                    af[s], bfr[u], acc[s][u], 0, 0, 0);
        __syncthreads();
    }

    // token bits: one word serves both u-columns (cols differ by 16, same >>5)
    const int colw = nb * 4 + wave;
    unsigned tb[16];
    #pragma unroll
    for (int s = 0; s < 4; s++)
        #pragma unroll
        for (int reg = 0; reg < 4; reg++) {
            const int row = mb * 64 + s * 16 + quad * 4 + reg;
            tb[s * 4 + reg] = tokbit[row * 64 + colw];
        }

    float* Cb = scsel + (size_t)h * 128 * S_;
    #pragma unroll
    for (int s = 0; s < 4; s++)
        #pragma unroll
        for (int u = 0; u < 2; u++) {
            const int col = nb * 128 + wave * 32 + u * 16 + mrow;
            const int sh = (u * 16 + mrow) & 31;
            #pragma unroll
            for (int reg = 0; reg < 4; reg++) {
                const int row = mb * 64 + s * 16 + quad * 4 + reg;
                if (((tb[s * 4 + reg] >> sh) & 1u) == (unsigned)c)
                    Cb[(size_t)row * S_ + col] = 0.125f * acc[s][u][reg];
            }
        }
}

// ---------------------------------------------------------------------------
// softmax over selected scores -> P (bf16 packed). Side jobs:
//   bh<512: arm pre_nxt=bs2 ; bh in [512,576): o_attn=0.
// ---------------------------------------------------------------------------
__global__ __launch_bounds__(256) void attn_soft(
    const float* __restrict__ scsel,          // (8,128,2048)
    const int*   __restrict__ tokens,         // (B,S)
    ushort_t* __restrict__ P,                 // (8,128,4096)
    float* __restrict__ o,                    // (B,512) -> zeroed
    const float* __restrict__ bs2,            // (4096)
    float* __restrict__ pre_nxt)              // (B,4096) -> init to bs2
{
    const int bh = blockIdx.x;
    const int b = bh >> 3, h = bh & 7;
    __shared__ float red[256];
    const int tid = threadIdx.x;

    if (bh < 512) {
        const int idx = bh * 256 + tid;
        const float4* bs4 = (const float4*)bs2;
        ((float4*)pre_nxt)[idx] = bs4[idx & 1023];
    } else if (bh < 576) {
        const int idx = (bh - 512) * 256 + tid;
        ((float4*)o)[idx] = make_float4(0.f, 0.f, 0.f, 0.f);
    }

    const float* scs = scsel + ((size_t)h * 128 + b) * S_;
    const int* trow = tokens + (size_t)b * S_;

    int tok[8]; float sel[8];
    float lmax = -1e30f;
    #pragma unroll
    for (int i = 0; i < 8; i++) {
        const int s = tid + i * 256;
        tok[i] = trow[s];
        sel[i] = scs[s];
        lmax = fmaxf(lmax, sel[i]);
    }
    red[tid] = lmax; __syncthreads();
    for (int off = 128; off > 0; off >>= 1) {
        if (tid < off) red[tid] = fmaxf(red[tid], red[tid + off]);
        __syncthreads();
    }
    const float mx = red[0];
    __syncthreads();

    float e[8];
    float lsum = 0.f;
    #pragma unroll
    for (int i = 0; i < 8; i++) {
        e[i] = expf(sel[i] - mx);
        lsum += e[i];
    }
    red[tid] = lsum; __syncthreads();
    for (int off = 128; off > 0; off >>= 1) {
        if (tid < off) red[tid] += red[tid + off];
        __syncthreads();
    }
    const float inv = 1.f / red[0];

    ushort_t* Pb = P + ((size_t)h * 128 + b) * 4096;
    #pragma unroll
    for (int i = 0; i < 8; i++) {
        const int s = tid + i * 256;
        const unsigned p = (unsigned)f2bf(e[i] * inv);
        const unsigned word = tok[i] ? (p << 16) : p;
        *(unsigned*)&Pb[s * 2] = word;
    }
}

// ---------------------------------------------------------------------------
// PV via MFMA. grid (2, 8, 16) = 256 blocks (kchunk 256). atomicAdd into o.
// ---------------------------------------------------------------------------
__global__ __launch_bounds__(256) void gemm_pv(
    const ushort_t* __restrict__ P,    // (8,128,4096)
    const ushort_t* __restrict__ VT,   // (8,64,4096)
    float* __restrict__ o)             // (128,512)
{
    const int mb = blockIdx.x, h = blockIdx.y, zb = blockIdx.z;
    const int k0 = zb * 256;
    __shared__ ushort_t As[64][40];
    __shared__ ushort_t Bs[64][40];

    const int tid  = threadIdx.x;
    const int wave = tid >> 6;
    const int lane = tid & 63;
    const int quad = lane >> 4;
    const int mrow = lane & 15;

    f32x4 acc[4];
    #pragma unroll
    for (int s = 0; s < 4; s++) acc[s] = (f32x4){0.f, 0.f, 0.f, 0.f};

    const int row = tid >> 2, kc = (tid & 3) * 8;
    const ushort_t* Ab = P  + ((size_t)h * 128 + mb * 64 + row) * 4096;
    const ushort_t* Bb = VT + ((size_t)h * 64 + row) * 4096;

    for (int kk = k0; kk < k0 + 256; kk += 32) {
        *(us8*)&As[row][kc] = *(const us8*)(Ab + kk + kc);
        *(us8*)&Bs[row][kc] = *(const us8*)(Bb + kk + kc);
        __syncthreads();
        bf16x8 bfr = *(const bf16x8*)&Bs[wave * 16 + mrow][quad * 8];
        #pragma unroll
        for (int s = 0; s < 4; s++) {
            bf16x8 af = *(const bf16x8*)&As[s * 16 + mrow][quad * 8];
            acc[s] = __builtin_amdgcn_mfma_f32_16x16x32_bf16(af, bfr, acc[s], 0, 0, 0);
        }
        __syncthreads();
    }

    const int col = h * 64 + wave * 16 + mrow;
    #pragma unroll
    for (int s = 0; s < 4; s++)
        #pragma unroll
        for (int reg = 0; reg < 4; reg++) {
            const int rowi = mb * 64 + s * 16 + quad * 4 + reg;
            atomicAdd(&o[(size_t)rowi * 512 + col], acc[s][reg]);
        }
}

// ---------------------------------------------------------------------------
// merged init: feats | act(+actb) | trace | sync tables | zerov | WoC cast |
//              bs2 | token bitmask
// ---------------------------------------------------------------------------
#define IA_FE 8192
#define IA_AC (IA_FE + 1024)
#define IA_TR (IA_AC + 6400)
#define IA_SY (IA_TR + 9)
#define IA_ZV (IA_SY + 1)
#define IA_WO (IA_ZV + 256)
#define IA_BS (IA_WO + 16)
#define IA_NB (IA_BS + 1024)
__global__ void init_all(const float* __restrict__ emb, const float* __restrict__ Wp,
                         const float* __restrict__ bp, float* __restrict__ f2,
                         const float* __restrict__ sa, float* __restrict__ act,
                         ushort_t* __restrict__ actb,
                         const float* __restrict__ st, float* __restrict__ trace,
                         const float* __restrict__ dec_act, const float* __restrict__ dec_out,
                         int* __restrict__ ijtab, float* __restrict__ r_act,
                         float* __restrict__ r_out, float* __restrict__ sqb_a,
                         float* __restrict__ sqb_o, float* __restrict__ zerov,
                         const float* __restrict__ Wo, ushort_t* __restrict__ WoC,
                         const float* __restrict__ bs, const float* __restrict__ bo,
                         const float* __restrict__ Ws, float* __restrict__ bs2,
                         const int* __restrict__ tokens, unsigned* __restrict__ tokbit)
{
    const int vb = blockIdx.x, tid = threadIdx.x;
    if (vb < IA_FE) {
        const int gid = vb * 256 + tid;
        const int k = gid & 511;
        const int s = (gid >> 9) & (S_ - 1);
        const int c = gid >> 20;
        const float th = 3.14159265358979323846f * (float)s / (float)(S_ - 1);
        f2[gid] = emb[c * 512 + k] + (-sinf(th)) * Wp[k] + cosf(th) * Wp[512 + k] + bp[k];
    } else if (vb < IA_AC) {
        const int gid = (vb - IA_FE) * 256 + tid;
        const int n = gid & 2047;
        const float v = sa[n];
        act[gid] = v;
        actb[gid] = f2bf(v);
    } else if (vb < IA_TR) {
        const int idx4 = (vb - IA_AC) * 256 + tid;
        ((float4*)trace)[idx4] = ((const float4*)st)[idx4 % 12800];
    } else if (vb < IA_SY) {
        const int p = (vb - IA_TR) * 256 + tid;
        if (p >= REP_) return;
        int i = 0, rem = p;
        while (rem >= NSY_ - i) { rem -= NSY_ - i; i++; }
        ijtab[p] = (i << 16) | (i + rem);
        const float ra = expf(-dec_act[p]);
        const float ro = expf(-dec_out[p]);
        r_act[p] = ra; r_out[p] = ro;
        float ba = 1.f, bo2 = 1.f;
        sqb_a[p] = 1.f;
        sqb_o[p] = 1.f;
        for (int t = 1; t < T_; t++) {
            ba  = ra * ba  + 1.f;
            bo2 = ro * bo2 + 1.f;
            sqb_a[(size_t)t * REP_ + p] = sqrtf(ba);
            sqb_o[(size_t)t * REP_ + p] = sqrtf(bo2);
        }
    } else if (vb < IA_ZV) {
        #pragma unroll
        for (int k = 0; k < 4; k++)
            ((float4*)zerov)[tid * 4 + k] = make_float4(0.f, 0.f, 0.f, 0.f);
    } else if (vb < IA_WO) {
        const int idx4 = (vb - IA_ZV) * 256 + tid;     // 65536 float4s
        float4 v = ((const float4*)Wo)[idx4];
        us4 w = { f2bf(v.x), f2bf(v.y), f2bf(v.z), f2bf(v.w) };
        ((us4*)WoC)[idx4] = w;
    } else if (vb < IA_BS) {
        const int n = (vb - IA_WO) * 256 + tid;        // 4096
        float acc = bs[n];
        for (int j = 0; j < 512; j++)
            acc += bo[j] * Ws[(size_t)j * 4096 + n];
        bs2[n] = acc;
    } else {
        const int blk = vb - IA_BS;                    // 0..1023
        const int b = blk >> 3, s0 = (blk & 7) * 256;
        const int tok = tokens[(size_t)b * S_ + s0 + tid];
        const unsigned long long m = __ballot(tok != 0);
        if ((tid & 63) == 0) {
            const int w = tid >> 6;
            tokbit[b * 64 + (s0 >> 5) + w * 2]     = (unsigned)m;
            tokbit[b * 64 + (s0 >> 5) + w * 2 + 1] = (unsigned)(m >> 32);
        }
    }
}

// ---------------------------------------------------------------------------
// merged 6-way transpose (f32 -> bf16)
// ---------------------------------------------------------------------------
__global__ __launch_bounds__(256) void transpose_all(
    const float* __restrict__ Wk, ushort_t* __restrict__ WkT,
    const float* __restrict__ Wv, ushort_t* __restrict__ WvT,
    const float* __restrict__ Wq, ushort_t* __restrict__ WqT,
    const float* __restrict__ Wo, ushort_t* __restrict__ WoT,
    const float* __restrict__ Ws, ushort_t* __restrict__ WsT,
    const float* __restrict__ Wout, ushort_t* __restrict__ WoutT)
{
    int bid = blockIdx.x;
    const float* in; ushort_t* out; int K, N;
    if      (bid <   256) {              in = Wk;   out = WkT;   K = 512;  N = 512;  }
    else if (bid <   512) { bid -=  256; in = Wv;   out = WvT;   K = 512;  N = 512;  }
    else if (bid <  1552) { bid -=  512; in = Wq;   out = WqT;   K = 2080; N = 512;  }
    else if (bid <  1808) { bid -= 1552; in = Wo;   out = WoT;   K = 512;  N = 512;  }
    else if (bid < 12048) { bid -= 1808; in = Ws;   out = WsT;   K = 2560; N = 4096; }
    else                  { bid -= 12048; in = Wout; out = WoutT; K = 2080; N = 4096; }
    const int bxw = N >> 5;
    const int bx = bid % bxw, by = bid / bxw;
    __shared__ float tile[32][33];
    const int k0 = by * 32, n0 = bx * 32;
    const int tx = threadIdx.x & 31, ty4 = (threadIdx.x >> 5) * 4;
    #pragma unroll
    for (int i = 0; i < 4; i++)
        tile[ty4 + i][tx] = in[(size_t)(k0 + ty4 + i) * N + n0 + tx];
    __syncthreads();
    #pragma unroll
    for (int i = 0; i < 4; i++)
        out[(size_t)(n0 + ty4 + i) * K + k0 + tx] = f2bf(tile[tx][ty4 + i]);
}

// ---------------------------------------------------------------------------
// merged casts: Ktab->Kb [0,2048) | build_vt [2048,10240) | Wcomb cast [10240,12288)
// ---------------------------------------------------------------------------
__global__ void cast3_kernel(const float* __restrict__ Ktab, ushort_t* __restrict__ Kb,
                             const float* __restrict__ Vtab, ushort_t* __restrict__ VT,
                             const float* __restrict__ Wcomb32, ushort_t* __restrict__ WcombTb)
{
    const int vb = blockIdx.x, tid = threadIdx.x;
    if (vb < 2048) {
        const int idx4 = vb * 256 + tid;               // 524288 float4s
        float4 v = ((const float4*)Ktab)[idx4];
        us4 w = { f2bf(v.x), f2bf(v.y), f2bf(v.z), f2bf(v.w) };
        ((us4*)Kb)[idx4] = w;
    } else if (vb < 10240) {
        const int gid = (vb - 2048) * 256 + tid;       // 8*64*4096
        const int k = gid & 4095;
        const int d = (gid >> 12) & 63;
        const int h = gid >> 18;
        const int s = k >> 1, c = k & 1;
        VT[gid] = f2bf(Vtab[((size_t)(c * S_ + s)) * 512 + h * 64 + d]);
    } else {
        const int idx4 = (vb - 10240) * 256 + tid;     // 524288 float4s
        float4 v = ((const float4*)Wcomb32)[idx4];
        us4 w = { f2bf(v.x), f2bf(v.y), f2bf(v.z), f2bf(v.w) };
        ((us4*)WcombTb)[idx4] = w;
    }
}

// ---------------------------------------------------------------------------
// prologue-only t=0 action-sync; y==8 block arms qbuf=bq and pre0=bs2
// ---------------------------------------------------------------------------
__global__ void sync_kernel(const float* __restrict__ act,
                            float* __restrict__ alpha,
                            const float* __restrict__ decay,
                            const int t, const int off,
                            ushort_t* __restrict__ sout,
                            float* __restrict__ ib1, const float* __restrict__ bias1, int iN1,
                            float* __restrict__ ib2, const float* __restrict__ bias2, int iN2)
{
    const int b = blockIdx.x;
    const int tid = threadIdx.x;
    if (blockIdx.y == 8) {
        if (ib1)
            for (int n = tid; n < iN1; n += 256)
                ib1[(size_t)b * iN1 + n] = bias1[n];
        if (ib2)
            for (int n = tid; n < iN2; n += 256)
                ib2[(size_t)b * iN2 + n] = bias2[n];
    }
    const int p = blockIdx.y * 256 + tid;
    if (p >= REP_) return;
    int i = 0, rem = p;
    while (rem >= NSY_ - i) { rem -= NSY_ - i; i++; }
    const int j = i + rem;
    const float si = act[(size_t)b * D_MODEL_ + off + i];
    const float sj = act[(size_t)b * D_MODEL_ + off + j];
    const float pair = si * sj;
    const float r = expf(-decay[p]);
    float a;
    if (t == 0) a = pair;
    else        a = r * alpha[(size_t)b * REP_ + p] + pair;
    alpha[(size_t)b * REP_ + p] = a;
    float bta = 1.f;
    for (int k = 0; k < t; k++) bta = r * bta + 1.f;
    sout[(size_t)b * REP_ + p] = f2bf(a / sqrtf(bta));
}

// ---------------------------------------------------------------------------
// state/trace/act, TT = compile-time iteration (circular trace, vectorizable).
// Epilogues: half==0: sync_out(TT) + predt=bout ; half==1: sync_act(TT+1)+qbuf=bq.
// ---------------------------------------------------------------------------
template<int TT>
__global__ __launch_bounds__(512, 2) void st_kernel(
    const float* __restrict__ pre,    // (B,4096)
    const float* __restrict__ g,
    const float* __restrict__ bt,
    float* __restrict__ trace,        // (B,2048,25) circular
    const float* __restrict__ ln_g,
    const float* __restrict__ ln_b,
    const float* __restrict__ Wn,
    const float* __restrict__ bn,
    const float* __restrict__ temp,
    ushort_t* __restrict__ actb,      // (B,2048) bf16
    const int* __restrict__ ijtab,
    const float* __restrict__ r_out,
    const float* __restrict__ sqb_out,
    float* __restrict__ a_o,
    ushort_t* __restrict__ s_outb,
    const float* __restrict__ bout,
    float* __restrict__ predt,
    const float* __restrict__ r_act,
    const float* __restrict__ sqb_act,
    float* __restrict__ a_a,
    ushort_t* __restrict__ s_actb,
    const float* __restrict__ bq,
    float* __restrict__ qbuf)
{
    const int b = blockIdx.x >> 1, half = blockIdx.x & 1;
    const int tid = threadIdx.x;          // 0..511
    __shared__ float v[D_MODEL_];
    __shared__ float r1[512], r2[512];
    __shared__ float sh_sync[64];
    float s1 = 0.f, s2 = 0.f;
    #pragma unroll
    for (int i = 0; i < 4; i++) {
        const int dd = tid + i * 512;
        const float g1 = pre[(size_t)b * 4096 + dd];
        const float g2 = pre[(size_t)b * 4096 + 2048 + dd];
        const float val = g1 * (1.f / (1.f + expf(-g2)));
        v[dd] = val; s1 += val; s2 += val * val;
    }
    r1[tid] = s1; r2[tid] = s2; __syncthreads();
    for (int off = 256; off > 0; off >>= 1) {
        if (tid < off) { r1[tid] += r1[tid + off]; r2[tid] += r2[tid + off]; }
        __syncthreads();
    }
    const float mu = r1[0] * (1.f / D_MODEL_);
    const float var = fmaxf(r2[0] * (1.f / D_MODEL_) - mu * mu, 0.f);
    const float sinv = 1.f / sqrtf(var + 1e-5f);
    const float tval = temp[0];

    #pragma unroll
    for (int i = 0; i < 2; i++) {
        const int n = half * 1024 + i * 512 + tid;
        const float sval = (v[n] - mu) * sinv * g[n] + bt[n];
        const int gid = b * 2048 + n;
        float* tr = trace + (size_t)gid * M_;
        float x[M_];
        #pragma unroll
        for (int m = 0; m < M_ - 1; m++) {
            int slot = TT + 1 + m;            // compile-time after unroll
            if (slot >= M_) slot -= M_;
            x[m] = tr[slot];
        }
        x[M_ - 1] = sval;
        tr[TT] = sval;                        // single write (circular head)
        float t1 = 0.f, t2 = 0.f;
        #pragma unroll
        for (int m = 0; m < M_; m++) { t1 += x[m]; t2 += x[m] * x[m]; }
        const float tmu = t1 * (1.f / M_);
        const float tvar = fmaxf(t2 * (1.f / M_) - tmu * tmu, 0.f);
        const float tinv = 1.f / sqrtf(tvar + 1e-5f);
        float y0 = bn[n * 2 + 0], y1 = bn[n * 2 + 1];
        #pragma unroll
        for (int m = 0; m < M_; m++) {
            const float xn = (x[m] - tmu) * tinv * ln_g[m] + ln_b[m];
            y0 += xn * Wn[(size_t)(m * 2 + 0) * D_MODEL_ + n];
            y1 += xn * Wn[(size_t)(m * 2 + 1) * D_MODEL_ + n];
        }
        const float a = y0 * (1.f / (1.f + expf(-y1))) / tval;
        actb[gid] = f2bf(a);
        if (half == 0) {
            if (i == 0 && tid < 64) sh_sync[tid] = a;            // act[b, 0..63]
        } else {
            if (i == 1 && tid >= 448) sh_sync[tid - 448] = a;    // act[b, 1984..2047]
        }
    }
    __syncthreads();

    if (half == 0) {
        for (int p = tid; p < REP_; p += 512) {
            const int ij = ijtab[p];
            const float pair = sh_sync[ij >> 16] * sh_sync[ij & 0xffff];
            const float r = r_out[p];
            float a2;
            if (TT == 0) a2 = pair;
            else         a2 = r * a_o[(size_t)b * REP_ + p] + pair;
            a_o[(size_t)b * REP_ + p] = a2;
            s_outb[(size_t)b * REP_ + p] = f2bf(a2 / sqb_out[(size_t)TT * REP_ + p]);
        }
        const float4* b4 = (const float4*)bout;
        float4* pd = (float4*)(predt + (size_t)b * 4096);
        for (int idx = tid; idx < 1024; idx += 512) pd[idx] = b4[idx];
    } else if (TT < T_ - 1) {
        for (int p = tid; p < REP_; p += 512) {
            const int ij = ijtab[p];
            const float pair = sh_sync[ij >> 16] * sh_sync[ij & 0xffff];
            const float r = r_act[p];
            float a2 = r * a_a[(size_t)b * REP_ + p] + pair;    // TT+1 >= 1
            a_a[(size_t)b * REP_ + p] = a2;
            s_actb[(size_t)b * REP_ + p] = f2bf(a2 / sqb_act[(size_t)(TT + 1) * REP_ + p]);
        }
        const float4* b4 = (const float4*)bq;
        float4* qb = (float4*)(qbuf + (size_t)b * 512);
        if (tid < 128) qb[tid] = b4[tid];
    }
}

// ---------------------------------------------------------------------------
// merged epilogue: entropy over all T + coalesced transposed output.
// grid = B blocks (one per b), 256 threads.
// ---------------------------------------------------------------------------
__global__ __launch_bounds__(256) void epilogue_kernel(
    const float* __restrict__ predst,  // (T, B*4096)
    float* __restrict__ dout)
{
    __shared__ float tile[T_][1024];
    __shared__ float red[256];
    __shared__ float certv[T_];
    const int b = blockIdx.x, tid = threadIdx.x;

    float esum[T_];
    #pragma unroll
    for (int t = 0; t < T_; t++) esum[t] = 0.f;

    for (int c4 = 0; c4 < 4; c4++) {
        const int row0 = c4 * 1024;
        #pragma unroll
        for (int t = 0; t < T_; t++) {
            float4 v = *(const float4*)(predst + (size_t)t * PRED_N
                                        + (size_t)b * 4096 + row0 + tid * 4);
            tile[t][tid * 4 + 0] = v.x; tile[t][tid * 4 + 1] = v.y;
            tile[t][tid * 4 + 2] = v.z; tile[t][tid * 4 + 3] = v.w;
            // entropy pairs (2s,2s+1): (v.x,v.y) and (v.z,v.w)
            {
                const float mm = fmaxf(v.x, v.y);
                const float z0 = expf(v.x - mm), z1 = expf(v.y - mm);
                const float Z = z0 + z1, lz = logf(Z);
                const float p0 = z0 / Z, p1 = z1 / Z;
                esum[t] += -(p0 * ((v.x - mm) - lz) + p1 * ((v.y - mm) - lz))
                           * 1.4426950408889634f;
            }
            {
                const float mm = fmaxf(v.z, v.w);
                const float z0 = expf(v.z - mm), z1 = expf(v.w - mm);
                const float Z = z0 + z1, lz = logf(Z);
                const float p0 = z0 / Z, p1 = z1 / Z;
                esum[t] += -(p0 * ((v.z - mm) - lz) + p1 * ((v.w - mm) - lz))
                           * 1.4426950408889634f;
            }
        }
        __syncthreads();
        float buf[40];
        #pragma unroll
        for (int r = 0; r < 4; r++)
            #pragma unroll
            for (int t = 0; t < T_; t++)
                buf[r * 10 + t] = tile[t][tid * 4 + r];
        float* dst = dout + ((size_t)b * 4096 + row0 + tid * 4) * T_;
        #pragma unroll
        for (int k = 0; k < 10; k++)
            *(float4*)(dst + k * 4) = make_float4(buf[4*k], buf[4*k+1], buf[4*k+2], buf[4*k+3]);
        __syncthreads();
    }

    #pragma unroll
    for (int t = 0; t < T_; t++) {
        red[tid] = esum[t]; __syncthreads();
        for (int off = 128; off > 0; off >>= 1) {
            if (tid < off) red[tid] += red[tid + off];
            __syncthreads();
        }
        if (tid == 0) certv[t] = red[0] * (1.f / S_);
        __syncthreads();
    }

    const size_t base = (size_t)PRED_N * T_;
    if (tid < T_)
        dout[base + (size_t)(b * 2 + 0) * T_ + tid] = certv[tid];
    else if (tid < 2 * T_)
        dout[base + (size_t)(b * 2 + 1) * T_ + (tid - T_)] = 1.f - certv[tid - T_];
}

// ===========================================================================
extern "C" void kernel_launch(void* const* d_in, const int* in_sizes, int n_in,
                              void* d_out, int out_size, void* d_ws, size_t ws_size,
                              hipStream_t stream)
{
    const int*   tokens    = (const int*)  d_in[0];
    const float* emb       = (const float*)d_in[1];
    const float* W_pos     = (const float*)d_in[2];
    const float* b_pos     = (const float*)d_in[3];
    const float* Wq        = (const float*)d_in[4];
    const float* bq        = (const float*)d_in[5];
    const float* Wk        = (const float*)d_in[6];
    const float* bk        = (const float*)d_in[7];
    const float* Wv        = (const float*)d_in[8];
    const float* bv        = (const float*)d_in[9];
    const float* Wo        = (const float*)d_in[10];
    const float* bo        = (const float*)d_in[11];
    const float* Ws        = (const float*)d_in[12];
    const float* bs        = (const float*)d_in[13];
    const float* ln_s_g    = (const float*)d_in[14];
    const float* ln_s_b    = (const float*)d_in[15];
    const float* ln_n_g    = (const float*)d_in[16];
    const float* ln_n_b    = (const float*)d_in[17];
    const float* Wn        = (const float*)d_in[18];
    const float* bn        = (const float*)d_in[19];
    const float* temp      = (const float*)d_in[20];
    const float* Wout      = (const float*)d_in[21];
    const float* bout      = (const float*)d_in[22];
    const float* start_act = (const float*)d_in[23];
    const float* start_tr  = (const float*)d_in[24];
    const float* dec_act   = (const float*)d_in[25];
    const float* dec_out   = (const float*)d_in[26];
    float* out = (float*)d_out;
    float* w = (float*)d_ws;

    // workspace layout (floats)
    size_t off = 0;
    float* f2     = w + off; off += (size_t)2 * S_ * 512;
    float* Ktab   = w + off; off += (size_t)2 * S_ * 512;
    float* Vtab   = w + off; off += (size_t)2 * S_ * 512;
    float* act    = w + off; off += (size_t)B_ * D_MODEL_;
    float* a_a    = w + off; off += (size_t)B_ * REP_;
    float* a_o    = w + off; off += (size_t)B_ * REP_;
    float* qbuf   = w + off; off += (size_t)B_ * 512;
    float* o_attn = w + off; off += (size_t)B_ * 512;
    float* pre0   = w + off; off += (size_t)B_ * 4096;
    float* pre1   = w + off; off += (size_t)B_ * 4096;
    float* trace  = w + off; off += (size_t)B_ * D_MODEL_ * M_;
    float* scsel  = w + off; off += (size_t)8 * 128 * S_;
    float* predst = w + off; off += (size_t)T_ * PRED_N;
    float* Wcomb32= w + off; off += (size_t)4096 * 512;
    float* bs2    = w + off; off += 4096;
    float* zerov  = w + off; off += 4096;
    ushort_t* s_actb = (ushort_t*)(w + off); off += (size_t)B_ * REP_ / 2;
    ushort_t* s_outb = (ushort_t*)(w + off); off += (size_t)B_ * REP_ / 2;
    ushort_t* actb   = (ushort_t*)(w + off); off += (size_t)B_ * D_MODEL_ / 2;
    __hip_bfloat16* Kb = (__hip_bfloat16*)(w + off); off += (size_t)S_ * 512;
    ushort_t* Pbuf  = (ushort_t*)(w + off); off += (size_t)8 * 128 * 4096 / 2;
    ushort_t* VT    = (ushort_t*)(w + off); off += (size_t)8 * 64 * 4096 / 2;
    ushort_t* WkT   = (ushort_t*)(w + off); off += (size_t)512 * 512 / 2;
    ushort_t* WvT   = (ushort_t*)(w + off); off += (size_t)512 * 512 / 2;
    ushort_t* WqT   = (ushort_t*)(w + off); off += (size_t)512 * REP_ / 2;
    ushort_t* WoT   = (ushort_t*)(w + off); off += (size_t)512 * 512 / 2;
    ushort_t* WsT   = (ushort_t*)(w + off); off += (size_t)4096 * 2560 / 2;
    ushort_t* WoutT = (ushort_t*)(w + off); off += (size_t)4096 * REP_ / 2;
    ushort_t* WoC   = (ushort_t*)(w + off); off += (size_t)512 * 512 / 2;
    ushort_t* WcombTb=(ushort_t*)(w + off); off += (size_t)4096 * 512 / 2;
    int*   ijtab  = (int*)(w + off); off += REP_;
    float* r_actT = w + off; off += REP_;
    float* r_outT = w + off; off += REP_;
    float* sqb_a  = w + off; off += (size_t)T_ * REP_;
    float* sqb_o  = w + off; off += (size_t)T_ * REP_;
    unsigned* tokbit = (unsigned*)(w + off); off += (size_t)B_ * 64 / 1;

    // ---- prologue (6 launches) ----
    init_all<<<IA_NB, 256, 0, stream>>>(
        emb, W_pos, b_pos, f2, start_act, act, actb, start_tr, trace,
        dec_act, dec_out, ijtab, r_actT, r_outT, sqb_a, sqb_o, zerov,
        Wo, WoC, bs, bo, Ws, bs2, tokens, tokbit);
    transpose_all<<<20368, 256, 0, stream>>>(
        Wk, WkT, Wv, WvT, Wq, WqT, Wo, WoT, Ws, WsT, Wout, WoutT);
    gemm3_kernel<<<dim3(4, 64, 3), 256, 0, stream>>>(
        f2, WkT, bk, Ktab, WvT, bv, Vtab, WsT, WoC, zerov, Wcomb32);
    cast3_kernel<<<12288, 256, 0, stream>>>(
        Ktab, (ushort_t*)Kb, Vtab, VT, Wcomb32, WcombTb);
    // t=0 action-sync; arms qbuf=bq and pre0=bs2
    sync_kernel<<<dim3(B_, 9), 256, 0, stream>>>(
        act, a_a, dec_act, 0, D_MODEL_ - NSY_, s_actb,
        qbuf, bq, 512, pre0, bs2, 4096);
    // Ws_act(0) + q(0) in one launch (atomic into armed targets)
    dual0_kernel<<<616, 256, 0, stream>>>(actb, WsT, pre0, s_actb, WqT, qbuf);

    // ---- T iterations (6 launches each) ----
    #define ST_ARGS(PC, PT) \
        PC, ln_s_g, ln_s_b, trace, ln_n_g, ln_n_b, Wn, bn, temp, actb, \
        ijtab, r_outT, sqb_o, a_o, s_outb, bout, PT, \
        r_actT, sqb_a, a_a, s_actb, bq, qbuf

    for (int t = 0; t < T_; t++) {
        float* pre_cur = (t & 1) ? pre1 : pre0;
        float* pre_nxt = (t & 1) ? pre0 : pre1;
        float* predt = predst + (size_t)t * PRED_N;

        gemm_qk_sel<<<dim3(S_ / 128, 2, 16), 256, 0, stream>>>(
            qbuf, (const ushort_t*)Kb, tokbit, scsel);
        // softmax + arms (pre_nxt=bs2, o_attn=0)
        attn_soft<<<B_ * H_, 256, 0, stream>>>(
            scsel, tokens, Pbuf, o_attn, bs2, pre_nxt);
        gemm_pv<<<dim3(2, 8, 16), 256, 0, stream>>>(Pbuf, VT, o_attn);

        // fused Wo+Ws_top: pre_cur += o_attn @ Wcomb (K=512, atomic)
        gemm_bf16<<<dim3(32, 2, 4), 256, 0, stream>>>(
            o_attn, 512, WcombTb, 512, bs2, pre_cur, 4096, B_, 4096, 512, 128);

        // state/trace/act + sync_out(t) + predt=bout + sync_act(t+1) + qbuf=bq
        switch (t) {
            case 0: st_kernel<0><<<B_ * 2, 512, 0, stream>>>(ST_ARGS(pre_cur, predt)); break;
            case 1: st_kernel<1><<<B_ * 2, 512, 0, stream>>>(ST_ARGS(pre_cur, predt)); break;
            case 2: st_kernel<2><<<B_ * 2, 512, 0, stream>>>(ST_ARGS(pre_cur, predt)); break;
            case 3: st_kernel<3><<<B_ * 2, 512, 0, stream>>>(ST_ARGS(pre_cur, predt)); break;
            case 4: st_kernel<4><<<B_ * 2, 512, 0, stream>>>(ST_ARGS(pre_cur, predt)); break;
            case 5: st_kernel<5><<<B_ * 2, 512, 0, stream>>>(ST_ARGS(pre_cur, predt)); break;
            case 6: st_kernel<6><<<B_ * 2, 512, 0, stream>>>(ST_ARGS(pre_cur, predt)); break;
            case 7: st_kernel<7><<<B_ * 2, 512, 0, stream>>>(ST_ARGS(pre_cur, predt)); break;
            case 8: st_kernel<8><<<B_ * 2, 512, 0, stream>>>(ST_ARGS(pre_cur, predt)); break;
            case 9: st_kernel<9><<<B_ * 2, 512, 0, stream>>>(ST_ARGS(pre_cur, predt)); break;
        }

        // merged tail: Wout(t) + q(t+1) + Ws_act(t+1)
        const int nblk = (t < T_ - 1) ? 936 : 320;
        triple_kernel<<<nblk, 256, 0, stream>>>(
            s_outb, WoutT, predt, s_actb, WqT, qbuf, actb, WsT, pre_nxt);
    }

    // merged entropy + transposed output (one launch)
    epilogue_kernel<<<B_, 256, 0, stream>>>(predst, out);
}